// Round 7
// baseline (1532.332 us; speedup 1.0000x reference)
//
#include <hip/hip_runtime.h>
#include <math.h>

#define NBV 65536
#define EV  1048576
#define BV  128
#define K1V 410
#define K2V 205
#define K3V 103
#define DNEG (-1.0e300)

__device__ __forceinline__ double dlrelu(double x){ return x > 0.0 ? x : 0.2*x; }

// ---------------- diagnostics sentinel (float32 out) ----------------
__global__ void k_sentinel(float* out, float v){
  int i = threadIdx.x;
  if (i < 128) out[i] = v;
}

// ---------------- utility ----------------
__global__ void k_cvt(const float* in, double* out, int n){
  int i = blockIdx.x*blockDim.x + threadIdx.x;
  if (i < n) out[i] = (double)in[i];
}

__global__ void k_fill1(double* p, int n){
  int i = blockIdx.x*blockDim.x + threadIdx.x;
  if (i < n) p[i] = 1.0;
}

__global__ void k_zero_i(int* p, int n){
  int i = blockIdx.x*blockDim.x + threadIdx.x;
  if (i < n) p[i] = 0;
}

// ---------------- CSR build (int atomics only) ----------------
__global__ void k_hist(const int* dst, int* dcnt){
  int e = blockIdx.x*blockDim.x + threadIdx.x;
  if (e < EV) atomicAdd(&dcnt[dst[e]], 1);
}

__global__ void k_scan1(const int* dcnt, int* rp, int* bsum){
  __shared__ int sc[256];
  int t = threadIdx.x, i = blockIdx.x*256 + t;
  int v = dcnt[i];
  sc[t] = v; __syncthreads();
  for (int o = 1; o < 256; o <<= 1){
    int x = (t >= o) ? sc[t-o] : 0;
    __syncthreads();
    sc[t] += x;
    __syncthreads();
  }
  rp[i] = sc[t];
  if (t == 255) bsum[blockIdx.x] = sc[t];
}

__global__ void k_scan2(int* bsum){
  __shared__ int sc[256];
  int t = threadIdx.x;
  int v = bsum[t];
  sc[t] = v; __syncthreads();
  for (int o = 1; o < 256; o <<= 1){
    int x = (t >= o) ? sc[t-o] : 0;
    __syncthreads();
    sc[t] += x;
    __syncthreads();
  }
  bsum[t] = sc[t] - v;
}

__global__ void k_scan3(int* rp, const int* dcnt, const int* bsum){
  int t = threadIdx.x, i = blockIdx.x*256 + t;
  rp[i] = rp[i] - dcnt[i] + bsum[blockIdx.x];
  if (i == 0) rp[NBV] = EV;
}

__global__ void k_scatter(const int* src, const int* dst, const int* rp, int* fill,
                          int* csr_src, int* csr_eid){
  int e = blockIdx.x*blockDim.x + threadIdx.x;
  if (e < EV){
    int d = dst[e];
    int pos = atomicAdd(&fill[d], 1);
    int slot = rp[d] + pos;
    csr_src[slot] = src[e];
    csr_eid[slot] = e;
  }
}

// ---------------- small precomputes ----------------
__global__ void k_invnorm(const float* wv, double* outv){
  __shared__ double sc[128];
  int t = threadIdx.x;
  double v = (double)wv[t];
  sc[t] = v*v; __syncthreads();
  for (int o = 64; o > 0; o >>= 1){ if (t < o) sc[t] += sc[t+o]; __syncthreads(); }
  if (t == 0) outv[0] = 1.0 / sqrt(sc[0]);
}

__global__ void k_ve(const float* g_we, const float* g_ae, double* ve){
  int t = threadIdx.x;
  if (t < 28){
    int ed = t >> 2, h = t & 3;
    double a = 0.0;
    for (int c = 0; c < 32; c++) a += (double)g_we[ed*128 + h*32 + c] * (double)g_ae[h*32 + c];
    ve[t] = a;
  }
}

__global__ void k_ale(const float* ea, const double* ve, double* ALE){
  int e = blockIdx.x*blockDim.x + threadIdx.x;
  if (e < EV){
    double a0=0.0,a1=0.0,a2=0.0,a3=0.0;
    for (int ed = 0; ed < 7; ed++){
      double x = (double)ea[e*7 + ed];
      a0 += x*ve[ed*4+0]; a1 += x*ve[ed*4+1]; a2 += x*ve[ed*4+2]; a3 += x*ve[ed*4+3];
    }
    ALE[(size_t)e*4+0] = a0; ALE[(size_t)e*4+1] = a1;
    ALE[(size_t)e*4+2] = a2; ALE[(size_t)e*4+3] = a3;
  }
}

// ---------------- SAGE mean aggregation (f64) ----------------
__global__ void k_sage_agg(const double* X, const double* nmask,
    const int* rp, const int* csr_src, double* AGG){
  int gid = blockIdx.x*256 + threadIdx.x;
  int i = gid >> 6, p = gid & 63;
  double ax=0.0, ay=0.0, cnt=0.0;
  if (nmask[i] > 0.0){
    int r0 = rp[i], r1 = rp[i+1];
    for (int s = r0; s < r1; s++){
      int sn = csr_src[s];
      if (nmask[sn] > 0.0){
        const double2 v = *(const double2*)&X[((size_t)sn << 7) + (p << 1)];
        ax += v.x; ay += v.y; cnt += 1.0;
      }
    }
  }
  double inv = 1.0 / fmax(cnt, 1.0);
  double2 o; o.x = ax*inv; o.y = ay*inv;
  *(double2*)&AGG[((size_t)i << 7) + (p << 1)] = o;
}

// ---------------- dual GEMM f64: OUT = act(A1@W1 [+ A2@W2] [+ b]) ----------------
__global__ void k_gemm(const double* A1, const double* A2,
    const float* W1, const float* W2, const float* bias,
    double* OUT, int has2, int relu, int hasb){
  __shared__ double a1[16][68];
  __shared__ double a2[16][68];
  __shared__ double w1[16][128];
  __shared__ double w2[16][128];
  int t = threadIdx.x;
  int n0 = blockIdx.x * 64;
  double acc[8][4];
  for (int r = 0; r < 8; r++)
    for (int j = 0; j < 4; j++) acc[r][j] = 0.0;
  int rb = (t & 7) * 8;
  int jb = (t >> 3) * 4;
  for (int kc = 0; kc < 128; kc += 16){
    __syncthreads();
    for (int ii = 0; ii < 4; ii++){
      int idx = t + 256*ii;
      int n = idx >> 4, kk = idx & 15;
      a1[kk][n] = A1[((size_t)(n0+n) << 7) + kc + kk];
      if (has2) a2[kk][n] = A2[((size_t)(n0+n) << 7) + kc + kk];
    }
    for (int ii = 0; ii < 8; ii++){
      int idx = t + 256*ii;
      int kk = idx >> 7, j = idx & 127;
      w1[kk][j] = (double)W1[(kc+kk)*128 + j];
      if (has2) w2[kk][j] = (double)W2[(kc+kk)*128 + j];
    }
    __syncthreads();
    for (int kk = 0; kk < 16; kk++){
      double wj0 = w1[kk][jb], wj1 = w1[kk][jb+1], wj2 = w1[kk][jb+2], wj3 = w1[kk][jb+3];
      for (int r = 0; r < 8; r++){
        double av = a1[kk][rb+r];
        acc[r][0] += av*wj0; acc[r][1] += av*wj1; acc[r][2] += av*wj2; acc[r][3] += av*wj3;
      }
      if (has2){
        double uj0 = w2[kk][jb], uj1 = w2[kk][jb+1], uj2 = w2[kk][jb+2], uj3 = w2[kk][jb+3];
        for (int r = 0; r < 8; r++){
          double bv = a2[kk][rb+r];
          acc[r][0] += bv*uj0; acc[r][1] += bv*uj1; acc[r][2] += bv*uj2; acc[r][3] += bv*uj3;
        }
      }
    }
  }
  double bj0=0.0,bj1=0.0,bj2=0.0,bj3=0.0;
  if (hasb){
    bj0 = (double)bias[jb+0]; bj1 = (double)bias[jb+1]; bj2 = (double)bias[jb+2]; bj3 = (double)bias[jb+3];
  }
  for (int r = 0; r < 8; r++){
    double o0 = acc[r][0]+bj0, o1 = acc[r][1]+bj1, o2 = acc[r][2]+bj2, o3 = acc[r][3]+bj3;
    if (relu){
      o0 = fmax(o0,0.0); o1 = fmax(o1,0.0); o2 = fmax(o2,0.0); o3 = fmax(o3,0.0);
    }
    size_t base = ((size_t)(n0+rb+r) << 7) + jb;
    OUT[base+0]=o0; OUT[base+1]=o1; OUT[base+2]=o2; OUT[base+3]=o3;
  }
}

// ---------------- scores ----------------
__global__ void k_score1(const double* X, const float* pw, const double* invn, double* s){
  int i = blockIdx.x*blockDim.x + threadIdx.x;
  if (i >= NBV) return;
  double a = 0.0;
  const double* xr = &X[(size_t)i << 7];
  for (int c = 0; c < 128; c++) a += xr[c] * (double)pw[c];
  s[i] = tanh(a * invn[0]);
}

__global__ void k_qr(const double* X, const float* wrel, const float* wroot, double* q, double* r){
  int i = blockIdx.x*blockDim.x + threadIdx.x;
  if (i >= NBV) return;
  double aq = 0.0, ar = 0.0;
  const double* xr = &X[(size_t)i << 7];
  for (int c = 0; c < 128; c++){
    double v = xr[c];
    aq += v * (double)wrel[c];
    ar += v * (double)wroot[c];
  }
  q[i] = aq; r[i] = ar;
}

__global__ void k_gconv(const double* q, const double* r, const double* nmask,
    const int* rp, const int* csr_src, const float* brel, double* s){
  int i = blockIdx.x*blockDim.x + threadIdx.x;
  if (i >= NBV) return;
  double acc = 0.0;
  if (nmask[i] > 0.0){
    int r0 = rp[i], r1 = rp[i+1];
    for (int t2 = r0; t2 < r1; t2++){
      int sn = csr_src[t2];
      if (nmask[sn] > 0.0) acc += q[sn];
    }
  }
  s[i] = tanh(acc + (double)brel[0] + r[i]);
}

// ---------------- top-k pool (stable tie-break == jax.lax.top_k) ----------------
__global__ void k_pool(const double* s, double* nmask, double* sel, int K){
  __shared__ double sc[512];
  int b = blockIdx.x, t = threadIdx.x;
  int i = b*512 + t;
  double nm = nmask[i];
  double sv = s[i];
  double ms = (nm > 0.0) ? sv : DNEG;
  sc[t] = ms;
  __syncthreads();
  int rank = 0;
  for (int j = 0; j < 512; j++){
    double o = sc[j];
    rank += ((o > ms) || (o == ms && j < t)) ? 1 : 0;
  }
  bool selb = rank < K;
  nmask[i] = selb ? 1.0 : 0.0;
  sel[i] = selb ? sv : 0.0;
}

// scale kept rows by score (in place) and write global-mean-pool — no atomics.
__global__ void k_scale_gap(double* X, const double* sel, double* gap, double invK){
  int b = blockIdx.x, c = threadIdx.x;
  double acc = 0.0;
  for (int n = 0; n < 512; n++){
    int i = b*512 + n;
    double v = X[((size_t)i << 7) + c] * sel[i];
    X[((size_t)i << 7) + c] = v;
    acc += v;
  }
  gap[b*128 + c] = acc * invK;
}

// ---------------- GAT pieces ----------------
__global__ void k_heads(const double* xs, const float* a_s, const float* a_d,
                        double* alS, double* alD){
  int gid = blockIdx.x*blockDim.x + threadIdx.x;
  int i = gid >> 2, h = gid & 3;
  if (i >= NBV) return;
  double as_ = 0.0, ad_ = 0.0;
  for (int c = 0; c < 32; c++){
    double v = xs[((size_t)i << 7) + h*32 + c];
    as_ += v * (double)a_s[h*32 + c];
    ad_ += v * (double)a_d[h*32 + c];
  }
  alS[gid] = as_; alD[gid] = ad_;
}

// edge-attr masked mean: stage 1 — per-block partials (no atomics)
__global__ void k_ea_part(const float* ea, const int* srcA, const int* dstA,
    const double* nmask, double* part){
  double p[8] = {0.0,0.0,0.0,0.0,0.0,0.0,0.0,0.0};
  for (int e = blockIdx.x*256 + threadIdx.x; e < EV; e += 256*256){
    if (nmask[srcA[e]] > 0.0 && nmask[dstA[e]] > 0.0){
      for (int d = 0; d < 7; d++) p[d] += (double)ea[e*7 + d];
      p[7] += 1.0;
    }
  }
  __shared__ double red[256];
  for (int comp = 0; comp < 8; comp++){
    red[threadIdx.x] = p[comp]; __syncthreads();
    for (int o = 128; o > 0; o >>= 1){ if (threadIdx.x < o) red[threadIdx.x] += red[threadIdx.x + o]; __syncthreads(); }
    if (threadIdx.x == 0) part[blockIdx.x*8 + comp] = red[0];
    __syncthreads();
  }
}

// stage 2 — reduce 256 partials
__global__ void k_ea_final(const double* part, double* easum){
  int h = threadIdx.x;
  if (h < 8){
    double s = 0.0;
    for (int b = 0; b < 256; b++) s += part[b*8 + h];
    easum[h] = s;
  }
}

__global__ void k_alse(const double* easum, const double* ve, double* alse){
  if (threadIdx.x == 0 && blockIdx.x == 0){
    double cnt = fmax(easum[7], 1.0);
    for (int h = 0; h < 4; h++){
      double s = 0.0;
      for (int ed = 0; ed < 7; ed++) s += (easum[ed]/cnt) * ve[ed*4 + h];
      alse[h] = s;
    }
  }
}

__global__ void k_gat(const double* xs, const double* alS, const double* alD,
    const double* ALE, const double* nmask, const int* rp, const int* csr_src,
    const int* csr_eid, const double* alse, const float* g_b, double* OUT){
  int gid = blockIdx.x*256 + threadIdx.x;
  int i = gid >> 2, h = gid & 3;
  double nmi = nmask[i];
  double ald_i = alD[i*4 + h];
  double als_i = alS[i*4 + h];
  double aself = (nmi > 0.0) ? dlrelu(als_i + ald_i + alse[h]) : DNEG;
  double m = aself;
  int r0 = rp[i], r1 = rp[i+1];
  const double2* xs2 = (const double2*)xs;
  if (nmi > 0.0){
    for (int t2 = r0; t2 < r1; t2++){
      int sn = csr_src[t2];
      if (nmask[sn] > 0.0){
        double a = dlrelu(alS[sn*4 + h] + ald_i + ALE[(size_t)csr_eid[t2]*4 + h]);
        m = fmax(m, a);
      }
    }
  }
  if (m < -1.0e299) m = 0.0;   // matches jnp.where(isfinite(m), m, 0)
  double den = 0.0;
  double2 acc[16];
  for (int c2 = 0; c2 < 16; c2++){ acc[c2].x = 0.0; acc[c2].y = 0.0; }
  if (nmi > 0.0){
    double es = exp(aself - m);
    den = es;
    for (int c2 = 0; c2 < 16; c2++){
      double2 v = xs2[(size_t)i*64 + h*16 + c2];
      acc[c2].x = es*v.x; acc[c2].y = es*v.y;
    }
    for (int t2 = r0; t2 < r1; t2++){
      int sn = csr_src[t2];
      if (nmask[sn] > 0.0){
        double a = dlrelu(alS[sn*4 + h] + ald_i + ALE[(size_t)csr_eid[t2]*4 + h]);
        double ex = exp(a - m);
        den += ex;
        for (int c2 = 0; c2 < 16; c2++){
          double2 v = xs2[(size_t)sn*64 + h*16 + c2];
          acc[c2].x += ex*v.x; acc[c2].y += ex*v.y;
        }
      }
    }
  }
  den = fmax(den, 1e-16);
  double rd = 1.0/den;
  for (int c2 = 0; c2 < 16; c2++){
    int cb = h*32 + c2*2;
    double o0 = fmax(acc[c2].x*rd + (double)g_b[cb+0], 0.0);
    double o1 = fmax(acc[c2].y*rd + (double)g_b[cb+1], 0.0);
    OUT[((size_t)i << 7) + cb]     = o0;
    OUT[((size_t)i << 7) + cb + 1] = o1;
  }
}

// ---------------- final MLP (f64 internal, f32 output) ----------------
__global__ void k_mlp(const double* x1g, const double* x2g, const double* x3g,
    const float* l1w, const float* l1b, const float* l2w, const float* l2b,
    const float* l3w, const float* l3b, float* out){
  __shared__ double hh[128];
  __shared__ double h2[128];
  __shared__ double h3[64];
  int b = blockIdx.x, t = threadIdx.x;
  hh[t] = x1g[b*128 + t] + x2g[b*128 + t] + x3g[b*128 + t];
  __syncthreads();
  double a = (double)l1b[t];
  for (int k = 0; k < 128; k++) a += hh[k] * (double)l1w[k*128 + t];
  h2[t] = fmax(a, 0.0);
  __syncthreads();
  if (t < 64){
    double a2 = (double)l2b[t];
    for (int k = 0; k < 128; k++) a2 += h2[k] * (double)l2w[k*64 + t];
    h3[t] = fmax(a2, 0.0);
  }
  __syncthreads();
  if (t == 0){
    double z = (double)l3b[0];
    for (int k = 0; k < 64; k++) z += h3[k] * (double)l3w[k];
    out[b] = (float)(1.0/(1.0 + exp(-z)));
  }
}

// ---------------- launch ----------------
extern "C" void kernel_launch(void* const* d_in, const int* in_sizes, int n_in,
                              void* d_out, int out_size, void* d_ws, size_t ws_size,
                              hipStream_t stream){
  // Reference dtypes: everything float32 except edge_index (int32).
  const float* x       = (const float*)d_in[0];
  const int*   ei      = (const int*)d_in[1];
  const float* ea      = (const float*)d_in[2];
  const float* c1_wl   = (const float*)d_in[3];
  const float* c1_bl   = (const float*)d_in[4];
  const float* c1_wr   = (const float*)d_in[5];
  const float* p1_w    = (const float*)d_in[6];
  const float* c2_wl   = (const float*)d_in[7];
  const float* c2_bl   = (const float*)d_in[8];
  const float* c2_wr   = (const float*)d_in[9];
  const float* p2_wrel = (const float*)d_in[10];
  const float* p2_brel = (const float*)d_in[11];
  const float* p2_wroot= (const float*)d_in[12];
  const float* g_w     = (const float*)d_in[13];
  const float* g_as    = (const float*)d_in[14];
  const float* g_ad    = (const float*)d_in[15];
  const float* g_we    = (const float*)d_in[16];
  const float* g_ae    = (const float*)d_in[17];
  const float* g_b     = (const float*)d_in[18];
  const float* p3_wrel = (const float*)d_in[19];
  const float* p3_brel = (const float*)d_in[20];
  const float* p3_wroot= (const float*)d_in[21];
  const float* l1_w    = (const float*)d_in[22];
  const float* l1_b    = (const float*)d_in[23];
  const float* l2_w    = (const float*)d_in[24];
  const float* l2_b    = (const float*)d_in[25];
  const float* l3_w    = (const float*)d_in[26];
  const float* l3_b    = (const float*)d_in[27];
  float* out = (float*)d_out;
  (void)in_sizes; (void)n_in; (void)out_size;

  // Workspace layout (f64, ~186 MB)
  char* w = (char*)d_ws;
  size_t off = 0;
  double* P    = (double*)(w + off); off += (size_t)NBV*128*8;
  double* Q    = (double*)(w + off); off += (size_t)NBV*128*8;
  double* ALE  = (double*)(w + off); off += (size_t)EV*4*8;
  double* sA   = (double*)(w + off); off += (size_t)NBV*8;
  double* sel  = (double*)(w + off); off += (size_t)NBV*8;
  double* qv   = (double*)(w + off); off += (size_t)NBV*8;
  double* rv   = (double*)(w + off); off += (size_t)NBV*8;
  double* nmask= (double*)(w + off); off += (size_t)NBV*8;
  double* alS  = (double*)(w + off); off += (size_t)NBV*4*8;
  double* alD  = (double*)(w + off); off += (size_t)NBV*4*8;
  double* x1g  = (double*)(w + off); off += (size_t)BV*128*8;
  double* x2g  = (double*)(w + off); off += (size_t)BV*128*8;
  double* x3g  = (double*)(w + off); off += (size_t)BV*128*8;
  double* sml  = (double*)(w + off); off += 64*8;      // [0]=invnorm [8..15]=easum [16..19]=alse [20..47]=ve
  double* part = (double*)(w + off); off += 2048*8;    // ea partials 256*8
  int* csr_src = (int*)(w + off); off += (size_t)EV*4;
  int* csr_eid = (int*)(w + off); off += (size_t)EV*4;
  int* rp      = (int*)(w + off); off += (size_t)(NBV+64)*4;
  int* dcnt    = (int*)(w + off); off += (size_t)(NBV+64)*4;
  int* bsum    = (int*)(w + off); off += 1024;
  size_t needed = off;

  // Diagnostic sentinel (overwritten by k_mlp on success):
  //   0.125 -> ws ok, pipeline broken; 0.875 -> workspace too small
  float sentinel = (ws_size >= needed) ? 0.125f : 0.875f;
  k_sentinel<<<1, 128, 0, stream>>>(out, sentinel);

  const int* srcA = ei;
  const int* dstA = ei + EV;

  // ---- setup ----
  k_cvt<<<(NBV*128)/256, 256, 0, stream>>>(x, P, NBV*128);
  k_fill1<<<NBV/256, 256, 0, stream>>>(nmask, NBV);
  k_zero_i<<<(NBV+256)/256, 256, 0, stream>>>(dcnt, NBV+1);
  k_hist<<<EV/256, 256, 0, stream>>>(dstA, dcnt);
  k_scan1<<<256, 256, 0, stream>>>(dcnt, rp, bsum);
  k_scan2<<<1, 256, 0, stream>>>(bsum);
  k_scan3<<<256, 256, 0, stream>>>(rp, dcnt, bsum);
  k_zero_i<<<(NBV+256)/256, 256, 0, stream>>>(dcnt, NBV+1);
  k_scatter<<<EV/256, 256, 0, stream>>>(srcA, dstA, rp, dcnt, csr_src, csr_eid);
  k_ve<<<1, 32, 0, stream>>>(g_we, g_ae, sml+20);
  k_ale<<<EV/256, 256, 0, stream>>>(ea, sml+20, ALE);

  // ---- block 1: SAGE -> TopK(410) -> gap  (X0=P, X1=Q) ----
  k_invnorm<<<1, 128, 0, stream>>>(p1_w, sml);
  k_sage_agg<<<(NBV*64)/256, 256, 0, stream>>>(P, nmask, rp, csr_src, Q);
  k_gemm<<<NBV/64, 256, 0, stream>>>(Q, P, c1_wl, c1_wr, c1_bl, Q, 1, 1, 1);
  k_score1<<<NBV/256, 256, 0, stream>>>(Q, p1_w, sml, sA);
  k_pool<<<BV, 512, 0, stream>>>(sA, nmask, sel, K1V);
  k_scale_gap<<<BV, 128, 0, stream>>>(Q, sel, x1g, 1.0/(double)K1V);

  // ---- block 2: SAGE -> SAGPool(205) -> gap  (X1=Q, X2=P) ----
  k_sage_agg<<<(NBV*64)/256, 256, 0, stream>>>(Q, nmask, rp, csr_src, P);
  k_gemm<<<NBV/64, 256, 0, stream>>>(P, Q, c2_wl, c2_wr, c2_bl, P, 1, 1, 1);
  k_qr<<<NBV/256, 256, 0, stream>>>(P, p2_wrel, p2_wroot, qv, rv);
  k_gconv<<<NBV/256, 256, 0, stream>>>(qv, rv, nmask, rp, csr_src, p2_brel, sA);
  k_pool<<<BV, 512, 0, stream>>>(sA, nmask, sel, K2V);
  k_scale_gap<<<BV, 128, 0, stream>>>(P, sel, x2g, 1.0/(double)K2V);

  // ---- block 3: GAT -> SAGPool(103) -> gap  (X2=P, xs=Q, gat-out=P) ----
  k_gemm<<<NBV/64, 256, 0, stream>>>(P, P, g_w, g_w, g_b, Q, 0, 0, 0);  // xs = X2 @ g_w
  k_heads<<<(NBV*4)/256, 256, 0, stream>>>(Q, g_as, g_ad, alS, alD);
  k_ea_part<<<256, 256, 0, stream>>>(ea, srcA, dstA, nmask, part);
  k_ea_final<<<1, 64, 0, stream>>>(part, sml+8);
  k_alse<<<1, 64, 0, stream>>>(sml+8, sml+20, sml+16);
  k_gat<<<(NBV*4)/256, 256, 0, stream>>>(Q, alS, alD, ALE, nmask, rp, csr_src, csr_eid, sml+16, g_b, P);
  k_qr<<<NBV/256, 256, 0, stream>>>(P, p3_wrel, p3_wroot, qv, rv);
  k_gconv<<<NBV/256, 256, 0, stream>>>(qv, rv, nmask, rp, csr_src, p3_brel, sA);
  k_pool<<<BV, 512, 0, stream>>>(sA, nmask, sel, K3V);
  k_scale_gap<<<BV, 128, 0, stream>>>(P, sel, x3g, 1.0/(double)K3V);

  // ---- readout MLP ----
  k_mlp<<<BV, 128, 0, stream>>>(x1g, x2g, x3g, l1_w, l1_b, l2_w, l2_b, l3_w, l3_b, out);
}

// Round 8
// 1126.871 us; speedup vs baseline: 1.3598x; 1.3598x over previous
//
#include <hip/hip_runtime.h>
#include <math.h>

#define NBV 65536
#define EV  1048576
#define BV  128
#define K1V 410
#define K2V 205
#define K3V 103
#define NEG_BIG (-1.0e38f)

__device__ __forceinline__ float lrelu(float x){ return x > 0.f ? x : 0.2f*x; }

// ---------------- diagnostics sentinel ----------------
__global__ void k_sentinel(float* out, float v){
  int i = threadIdx.x;
  if (i < 128) out[i] = v;
}

// ---------------- utility ----------------
__global__ void k_fill1(float* p, int n){
  int i = blockIdx.x*blockDim.x + threadIdx.x;
  if (i < n) p[i] = 1.f;
}

__global__ void k_zero_i(int* p, int n){
  int i = blockIdx.x*blockDim.x + threadIdx.x;
  if (i < n) p[i] = 0;
}

// ---------------- CSR build (int atomics only) ----------------
__global__ void k_hist(const int* dst, int* dcnt){
  int e = blockIdx.x*blockDim.x + threadIdx.x;
  if (e < EV) atomicAdd(&dcnt[dst[e]], 1);
}

__global__ void k_scan1(const int* dcnt, int* rp, int* bsum){
  __shared__ int sc[256];
  int t = threadIdx.x, i = blockIdx.x*256 + t;
  int v = dcnt[i];
  sc[t] = v; __syncthreads();
  for (int o = 1; o < 256; o <<= 1){
    int x = (t >= o) ? sc[t-o] : 0;
    __syncthreads();
    sc[t] += x;
    __syncthreads();
  }
  rp[i] = sc[t];
  if (t == 255) bsum[blockIdx.x] = sc[t];
}

__global__ void k_scan2(int* bsum){
  __shared__ int sc[256];
  int t = threadIdx.x;
  int v = bsum[t];
  sc[t] = v; __syncthreads();
  for (int o = 1; o < 256; o <<= 1){
    int x = (t >= o) ? sc[t-o] : 0;
    __syncthreads();
    sc[t] += x;
    __syncthreads();
  }
  bsum[t] = sc[t] - v;
}

__global__ void k_scan3(int* rp, const int* dcnt, const int* bsum){
  int t = threadIdx.x, i = blockIdx.x*256 + t;
  rp[i] = rp[i] - dcnt[i] + bsum[blockIdx.x];
  if (i == 0) rp[NBV] = EV;
}

__global__ void k_scatter(const int* src, const int* dst, const int* rp, int* fill,
                          int* csr_src, int* csr_eid){
  int e = blockIdx.x*blockDim.x + threadIdx.x;
  if (e < EV){
    int d = dst[e];
    int pos = atomicAdd(&fill[d], 1);
    int slot = rp[d] + pos;
    csr_src[slot] = src[e];
    csr_eid[slot] = e;
  }
}

// ---------------- small precomputes ----------------
__global__ void k_invnorm(const float* wv, float* outv){
  __shared__ float sc[128];
  int t = threadIdx.x;
  float v = wv[t];
  sc[t] = v*v; __syncthreads();
  for (int o = 64; o > 0; o >>= 1){ if (t < o) sc[t] += sc[t+o]; __syncthreads(); }
  if (t == 0) outv[0] = 1.f / sqrtf(sc[0]);
}

__global__ void k_ve(const float* g_we, const float* g_ae, float* ve){
  int t = threadIdx.x;
  if (t < 28){
    int ed = t >> 2, h = t & 3;
    float a = 0.f;
    for (int c = 0; c < 32; c++) a += g_we[ed*128 + h*32 + c] * g_ae[h*32 + c];
    ve[t] = a;
  }
}

__global__ void k_ale(const float* ea, const float* ve, float* ALE){
  int e = blockIdx.x*blockDim.x + threadIdx.x;
  if (e < EV){
    float a0=0.f,a1=0.f,a2=0.f,a3=0.f;
    for (int ed = 0; ed < 7; ed++){
      float x = ea[e*7 + ed];
      a0 += x*ve[ed*4+0]; a1 += x*ve[ed*4+1]; a2 += x*ve[ed*4+2]; a3 += x*ve[ed*4+3];
    }
    float4 o; o.x=a0; o.y=a1; o.z=a2; o.w=a3;
    *(float4*)&ALE[(size_t)e*4] = o;
  }
}

// ---------------- SAGE mean aggregation (f32, float4) ----------------
__global__ void __launch_bounds__(256) k_sage_agg(const float* X, const float* nmask,
    const int* rp, const int* csr_src, float* AGG){
  int gid = blockIdx.x*256 + threadIdx.x;   // NBV*32 threads: (node, c4)
  int i = gid >> 5, c4 = gid & 31;
  float ax=0.f,ay=0.f,az=0.f,aw=0.f,cnt=0.f;
  if (nmask[i] > 0.f){
    int r0 = rp[i], r1 = rp[i+1];
    for (int s = r0; s < r1; s++){
      int sn = csr_src[s];
      if (nmask[sn] > 0.f){
        const float4 v = *(const float4*)&X[((size_t)sn << 7) + (c4 << 2)];
        ax += v.x; ay += v.y; az += v.z; aw += v.w; cnt += 1.f;
      }
    }
  }
  float inv = 1.f / fmaxf(cnt, 1.f);
  float4 o; o.x = ax*inv; o.y = ay*inv; o.z = az*inv; o.w = aw*inv;
  *(float4*)&AGG[((size_t)i << 7) + (c4 << 2)] = o;
}

// ---------------- dual GEMM f32: OUT = act(A1@W1 [+ A2@W2] [+ b]) ----------------
__global__ void __launch_bounds__(256) k_gemm(const float* A1, const float* A2,
    const float* W1, const float* W2, const float* bias,
    float* OUT, int has2, int relu, int hasb){
  __shared__ float a1[16][68];
  __shared__ float a2[16][68];
  __shared__ float w1[16][128];
  __shared__ float w2[16][128];
  int t = threadIdx.x;
  int n0 = blockIdx.x * 64;
  float acc[8][4];
  for (int r = 0; r < 8; r++)
    for (int j = 0; j < 4; j++) acc[r][j] = 0.f;
  int rb = (t & 7) * 8;
  int jb = (t >> 3) * 4;
  for (int kc = 0; kc < 128; kc += 16){
    __syncthreads();
    for (int ii = 0; ii < 4; ii++){
      int idx = t + 256*ii;
      int n = idx >> 4, kk = idx & 15;
      a1[kk][n] = A1[((size_t)(n0+n) << 7) + kc + kk];
      if (has2) a2[kk][n] = A2[((size_t)(n0+n) << 7) + kc + kk];
    }
    for (int ii = 0; ii < 8; ii++){
      int idx = t + 256*ii;
      int kk = idx >> 7, j = idx & 127;
      w1[kk][j] = W1[(kc+kk)*128 + j];
      if (has2) w2[kk][j] = W2[(kc+kk)*128 + j];
    }
    __syncthreads();
    for (int kk = 0; kk < 16; kk++){
      float4 wA = *(const float4*)&w1[kk][jb];
      float4 aL = *(const float4*)&a1[kk][rb];
      float4 aH = *(const float4*)&a1[kk][rb+4];
      float av0=aL.x,av1=aL.y,av2=aL.z,av3=aL.w,av4=aH.x,av5=aH.y,av6=aH.z,av7=aH.w;
      acc[0][0]+=av0*wA.x; acc[0][1]+=av0*wA.y; acc[0][2]+=av0*wA.z; acc[0][3]+=av0*wA.w;
      acc[1][0]+=av1*wA.x; acc[1][1]+=av1*wA.y; acc[1][2]+=av1*wA.z; acc[1][3]+=av1*wA.w;
      acc[2][0]+=av2*wA.x; acc[2][1]+=av2*wA.y; acc[2][2]+=av2*wA.z; acc[2][3]+=av2*wA.w;
      acc[3][0]+=av3*wA.x; acc[3][1]+=av3*wA.y; acc[3][2]+=av3*wA.z; acc[3][3]+=av3*wA.w;
      acc[4][0]+=av4*wA.x; acc[4][1]+=av4*wA.y; acc[4][2]+=av4*wA.z; acc[4][3]+=av4*wA.w;
      acc[5][0]+=av5*wA.x; acc[5][1]+=av5*wA.y; acc[5][2]+=av5*wA.z; acc[5][3]+=av5*wA.w;
      acc[6][0]+=av6*wA.x; acc[6][1]+=av6*wA.y; acc[6][2]+=av6*wA.z; acc[6][3]+=av6*wA.w;
      acc[7][0]+=av7*wA.x; acc[7][1]+=av7*wA.y; acc[7][2]+=av7*wA.z; acc[7][3]+=av7*wA.w;
      if (has2){
        float4 wB = *(const float4*)&w2[kk][jb];
        float4 bL = *(const float4*)&a2[kk][rb];
        float4 bH = *(const float4*)&a2[kk][rb+4];
        float bv0=bL.x,bv1=bL.y,bv2=bL.z,bv3=bL.w,bv4=bH.x,bv5=bH.y,bv6=bH.z,bv7=bH.w;
        acc[0][0]+=bv0*wB.x; acc[0][1]+=bv0*wB.y; acc[0][2]+=bv0*wB.z; acc[0][3]+=bv0*wB.w;
        acc[1][0]+=bv1*wB.x; acc[1][1]+=bv1*wB.y; acc[1][2]+=bv1*wB.z; acc[1][3]+=bv1*wB.w;
        acc[2][0]+=bv2*wB.x; acc[2][1]+=bv2*wB.y; acc[2][2]+=bv2*wB.z; acc[2][3]+=bv2*wB.w;
        acc[3][0]+=bv3*wB.x; acc[3][1]+=bv3*wB.y; acc[3][2]+=bv3*wB.z; acc[3][3]+=bv3*wB.w;
        acc[4][0]+=bv4*wB.x; acc[4][1]+=bv4*wB.y; acc[4][2]+=bv4*wB.z; acc[4][3]+=bv4*wB.w;
        acc[5][0]+=bv5*wB.x; acc[5][1]+=bv5*wB.y; acc[5][2]+=bv5*wB.z; acc[5][3]+=bv5*wB.w;
        acc[6][0]+=bv6*wB.x; acc[6][1]+=bv6*wB.y; acc[6][2]+=bv6*wB.z; acc[6][3]+=bv6*wB.w;
        acc[7][0]+=bv7*wB.x; acc[7][1]+=bv7*wB.y; acc[7][2]+=bv7*wB.z; acc[7][3]+=bv7*wB.w;
      }
    }
  }
  float bj0=0.f,bj1=0.f,bj2=0.f,bj3=0.f;
  if (hasb){
    bj0 = bias[jb+0]; bj1 = bias[jb+1]; bj2 = bias[jb+2]; bj3 = bias[jb+3];
  }
  for (int r = 0; r < 8; r++){
    float4 o;
    o.x = acc[r][0]+bj0; o.y = acc[r][1]+bj1; o.z = acc[r][2]+bj2; o.w = acc[r][3]+bj3;
    if (relu){
      o.x = fmaxf(o.x,0.f); o.y = fmaxf(o.y,0.f); o.z = fmaxf(o.z,0.f); o.w = fmaxf(o.w,0.f);
    }
    *(float4*)&OUT[((size_t)(n0+rb+r) << 7) + jb] = o;
  }
}

// ---------------- scores ----------------
__global__ void k_score1(const float* X, const float* pw, const float* invn, float* s){
  int i = blockIdx.x*blockDim.x + threadIdx.x;
  if (i >= NBV) return;
  float a = 0.f;
  const float4* x4 = (const float4*)&X[(size_t)i << 7];
  for (int c4 = 0; c4 < 32; c4++){
    float4 v = x4[c4];
    a += v.x*pw[c4*4] + v.y*pw[c4*4+1] + v.z*pw[c4*4+2] + v.w*pw[c4*4+3];
  }
  s[i] = tanhf(a * invn[0]);
}

__global__ void k_qr(const float* X, const float* wrel, const float* wroot, float* q, float* r){
  int i = blockIdx.x*blockDim.x + threadIdx.x;
  if (i >= NBV) return;
  float aq = 0.f, ar = 0.f;
  const float4* x4 = (const float4*)&X[(size_t)i << 7];
  for (int c4 = 0; c4 < 32; c4++){
    float4 v = x4[c4];
    aq += v.x*wrel[c4*4] + v.y*wrel[c4*4+1] + v.z*wrel[c4*4+2] + v.w*wrel[c4*4+3];
    ar += v.x*wroot[c4*4] + v.y*wroot[c4*4+1] + v.z*wroot[c4*4+2] + v.w*wroot[c4*4+3];
  }
  q[i] = aq; r[i] = ar;
}

__global__ void k_gconv(const float* q, const float* r, const float* nmask,
    const int* rp, const int* csr_src, const float* brel, float* s){
  int i = blockIdx.x*blockDim.x + threadIdx.x;
  if (i >= NBV) return;
  float acc = 0.f;
  if (nmask[i] > 0.f){
    int r0 = rp[i], r1 = rp[i+1];
    for (int t2 = r0; t2 < r1; t2++){
      int sn = csr_src[t2];
      if (nmask[sn] > 0.f) acc += q[sn];
    }
  }
  s[i] = tanhf(acc + brel[0] + r[i]);
}

// ---------------- top-k pool (stable tie-break == jax.lax.top_k) ----------------
__global__ void __launch_bounds__(512) k_pool(const float* s, float* nmask, float* sel, int K){
  __shared__ float sc[512];
  int b = blockIdx.x, t = threadIdx.x;
  int i = b*512 + t;
  float nm = nmask[i];
  float sv = s[i];
  float ms = (nm > 0.f) ? sv : NEG_BIG;
  sc[t] = ms;
  __syncthreads();
  int rank = 0;
  for (int j = 0; j < 512; j++){
    float o = sc[j];
    rank += ((o > ms) || (o == ms && j < t)) ? 1 : 0;
  }
  bool selb = rank < K;
  nmask[i] = selb ? 1.f : 0.f;
  sel[i] = selb ? sv : 0.f;
}

// scale kept rows by score (in place) and write global-mean-pool — no atomics.
__global__ void __launch_bounds__(128) k_scale_gap(float* X, const float* sel, float* gap, float invK){
  int b = blockIdx.x, c = threadIdx.x;
  float acc = 0.f;
  for (int n = 0; n < 512; n++){
    int i = b*512 + n;
    float v = X[((size_t)i << 7) + c] * sel[i];
    X[((size_t)i << 7) + c] = v;
    acc += v;
  }
  gap[b*128 + c] = acc * invK;
}

// ---------------- GAT pieces ----------------
__global__ void k_heads(const float* xs, const float* a_s, const float* a_d,
                        float* alS, float* alD){
  int gid = blockIdx.x*blockDim.x + threadIdx.x;
  int i = gid >> 2, h = gid & 3;
  if (i >= NBV) return;
  float as_ = 0.f, ad_ = 0.f;
  for (int c = 0; c < 32; c++){
    float v = xs[((size_t)i << 7) + h*32 + c];
    as_ += v * a_s[h*32 + c];
    ad_ += v * a_d[h*32 + c];
  }
  alS[gid] = as_; alD[gid] = ad_;
}

// edge-attr masked mean: stage 1 — per-block partials (no atomics)
__global__ void __launch_bounds__(256) k_ea_part(const float* ea, const int* srcA, const int* dstA,
    const float* nmask, float* part){
  float p[8] = {0.f,0.f,0.f,0.f,0.f,0.f,0.f,0.f};
  for (int e = blockIdx.x*256 + threadIdx.x; e < EV; e += 256*256){
    if (nmask[srcA[e]] > 0.f && nmask[dstA[e]] > 0.f){
      for (int d = 0; d < 7; d++) p[d] += ea[e*7 + d];
      p[7] += 1.f;
    }
  }
  __shared__ float red[256];
  for (int comp = 0; comp < 8; comp++){
    red[threadIdx.x] = p[comp]; __syncthreads();
    for (int o = 128; o > 0; o >>= 1){ if (threadIdx.x < o) red[threadIdx.x] += red[threadIdx.x + o]; __syncthreads(); }
    if (threadIdx.x == 0) part[blockIdx.x*8 + comp] = red[0];
    __syncthreads();
  }
}

__global__ void k_ea_final(const float* part, float* easum){
  int h = threadIdx.x;
  if (h < 8){
    float s = 0.f;
    for (int b = 0; b < 256; b++) s += part[b*8 + h];
    easum[h] = s;
  }
}

__global__ void k_alse(const float* easum, const float* ve, float* alse){
  if (threadIdx.x == 0 && blockIdx.x == 0){
    float cnt = fmaxf(easum[7], 1.f);
    for (int h = 0; h < 4; h++){
      float s = 0.f;
      for (int ed = 0; ed < 7; ed++) s += (easum[ed]/cnt) * ve[ed*4 + h];
      alse[h] = s;
    }
  }
}

__global__ void __launch_bounds__(256) k_gat(const float* xs, const float* alS, const float* alD,
    const float* ALE, const float* nmask, const int* rp, const int* csr_src,
    const int* csr_eid, const float* alse, const float* g_b, float* OUT){
  int gid = blockIdx.x*256 + threadIdx.x;
  int i = gid >> 2, h = gid & 3;
  float nmi = nmask[i];
  float ald_i = alD[i*4 + h];
  float als_i = alS[i*4 + h];
  float aself = (nmi > 0.f) ? lrelu(als_i + ald_i + alse[h]) : NEG_BIG;
  float m = aself;
  int r0 = rp[i], r1 = rp[i+1];
  const float4* xs4 = (const float4*)xs;
  if (nmi > 0.f){
    for (int t2 = r0; t2 < r1; t2++){
      int sn = csr_src[t2];
      if (nmask[sn] > 0.f){
        float a = lrelu(alS[sn*4 + h] + ald_i + ALE[(size_t)csr_eid[t2]*4 + h]);
        m = fmaxf(m, a);
      }
    }
  }
  if (m < -1.0e37f) m = 0.f;   // matches jnp.where(isfinite(m), m, 0)
  float den = 0.f;
  float4 acc[8];
  for (int c4 = 0; c4 < 8; c4++){ acc[c4].x=0.f; acc[c4].y=0.f; acc[c4].z=0.f; acc[c4].w=0.f; }
  if (nmi > 0.f){
    float es = expf(aself - m);
    den = es;
    for (int c4 = 0; c4 < 8; c4++){
      float4 v = xs4[(size_t)i*32 + h*8 + c4];
      acc[c4].x = es*v.x; acc[c4].y = es*v.y; acc[c4].z = es*v.z; acc[c4].w = es*v.w;
    }
    for (int t2 = r0; t2 < r1; t2++){
      int sn = csr_src[t2];
      if (nmask[sn] > 0.f){
        float a = lrelu(alS[sn*4 + h] + ald_i + ALE[(size_t)csr_eid[t2]*4 + h]);
        float ex = expf(a - m);
        den += ex;
        for (int c4 = 0; c4 < 8; c4++){
          float4 v = xs4[(size_t)sn*32 + h*8 + c4];
          acc[c4].x += ex*v.x; acc[c4].y += ex*v.y; acc[c4].z += ex*v.z; acc[c4].w += ex*v.w;
        }
      }
    }
  }
  den = fmaxf(den, 1e-16f);
  float rd = 1.f/den;
  for (int c4 = 0; c4 < 8; c4++){
    int cb = h*32 + c4*4;
    float4 o;
    o.x = fmaxf(acc[c4].x*rd + g_b[cb+0], 0.f);
    o.y = fmaxf(acc[c4].y*rd + g_b[cb+1], 0.f);
    o.z = fmaxf(acc[c4].z*rd + g_b[cb+2], 0.f);
    o.w = fmaxf(acc[c4].w*rd + g_b[cb+3], 0.f);
    *(float4*)&OUT[((size_t)i << 7) + cb] = o;
  }
}

// ---------------- final MLP ----------------
__global__ void __launch_bounds__(128) k_mlp(const float* x1g, const float* x2g, const float* x3g,
    const float* l1w, const float* l1b, const float* l2w, const float* l2b,
    const float* l3w, const float* l3b, float* out){
  __shared__ float hh[128];
  __shared__ float h2[128];
  __shared__ float h3[64];
  int b = blockIdx.x, t = threadIdx.x;
  hh[t] = x1g[b*128 + t] + x2g[b*128 + t] + x3g[b*128 + t];
  __syncthreads();
  float a = l1b[t];
  for (int k = 0; k < 128; k++) a += hh[k] * l1w[k*128 + t];
  h2[t] = fmaxf(a, 0.f);
  __syncthreads();
  if (t < 64){
    float a2 = l2b[t];
    for (int k = 0; k < 128; k++) a2 += h2[k] * l2w[k*64 + t];
    h3[t] = fmaxf(a2, 0.f);
  }
  __syncthreads();
  if (t == 0){
    float z = l3b[0];
    for (int k = 0; k < 64; k++) z += h3[k] * l3w[k];
    out[b] = 1.f/(1.f + expf(-z));
  }
}

// ---------------- launch ----------------
extern "C" void kernel_launch(void* const* d_in, const int* in_sizes, int n_in,
                              void* d_out, int out_size, void* d_ws, size_t ws_size,
                              hipStream_t stream){
  const float* x       = (const float*)d_in[0];
  const int*   ei      = (const int*)d_in[1];
  const float* ea      = (const float*)d_in[2];
  const float* c1_wl   = (const float*)d_in[3];
  const float* c1_bl   = (const float*)d_in[4];
  const float* c1_wr   = (const float*)d_in[5];
  const float* p1_w    = (const float*)d_in[6];
  const float* c2_wl   = (const float*)d_in[7];
  const float* c2_bl   = (const float*)d_in[8];
  const float* c2_wr   = (const float*)d_in[9];
  const float* p2_wrel = (const float*)d_in[10];
  const float* p2_brel = (const float*)d_in[11];
  const float* p2_wroot= (const float*)d_in[12];
  const float* g_w     = (const float*)d_in[13];
  const float* g_as    = (const float*)d_in[14];
  const float* g_ad    = (const float*)d_in[15];
  const float* g_we    = (const float*)d_in[16];
  const float* g_ae    = (const float*)d_in[17];
  const float* g_b     = (const float*)d_in[18];
  const float* p3_wrel = (const float*)d_in[19];
  const float* p3_brel = (const float*)d_in[20];
  const float* p3_wroot= (const float*)d_in[21];
  const float* l1_w    = (const float*)d_in[22];
  const float* l1_b    = (const float*)d_in[23];
  const float* l2_w    = (const float*)d_in[24];
  const float* l2_b    = (const float*)d_in[25];
  const float* l3_w    = (const float*)d_in[26];
  const float* l3_b    = (const float*)d_in[27];
  float* out = (float*)d_out;
  (void)in_sizes; (void)n_in; (void)out_size;

  // Workspace layout (f32, ~136 MB; ws_size >= 186 MB proven in r7)
  char* w = (char*)d_ws;
  size_t off = 0;
  float* AGG  = (float*)(w + off); off += (size_t)NBV*128*4;
  float* F1   = (float*)(w + off); off += (size_t)NBV*128*4;
  float* F2   = (float*)(w + off); off += (size_t)NBV*128*4;
  float* ALE  = (float*)(w + off); off += (size_t)EV*4*4;
  float* sA   = (float*)(w + off); off += (size_t)NBV*4;
  float* sel  = (float*)(w + off); off += (size_t)NBV*4;
  float* qv   = (float*)(w + off); off += (size_t)NBV*4;
  float* rv   = (float*)(w + off); off += (size_t)NBV*4;
  float* nmask= (float*)(w + off); off += (size_t)NBV*4;
  float* alS  = (float*)(w + off); off += (size_t)NBV*4*4;
  float* alD  = (float*)(w + off); off += (size_t)NBV*4*4;
  float* x1g  = (float*)(w + off); off += (size_t)BV*128*4;
  float* x2g  = (float*)(w + off); off += (size_t)BV*128*4;
  float* x3g  = (float*)(w + off); off += (size_t)BV*128*4;
  float* sml  = (float*)(w + off); off += 64*4;      // [0]=invnorm [8..15]=easum [16..19]=alse [20..47]=ve
  float* part = (float*)(w + off); off += 2048*4;
  int* csr_src = (int*)(w + off); off += (size_t)EV*4;
  int* csr_eid = (int*)(w + off); off += (size_t)EV*4;
  int* rp      = (int*)(w + off); off += (size_t)(NBV+64)*4;
  int* dcnt    = (int*)(w + off); off += (size_t)(NBV+64)*4;
  int* bsum    = (int*)(w + off); off += 1024;
  size_t needed = off;

  float sentinel = (ws_size >= needed) ? 0.125f : 0.875f;
  k_sentinel<<<1, 128, 0, stream>>>(out, sentinel);

  const int* srcA = ei;
  const int* dstA = ei + EV;

  // ---- setup ----
  k_fill1<<<NBV/256, 256, 0, stream>>>(nmask, NBV);
  k_zero_i<<<(NBV+256)/256, 256, 0, stream>>>(dcnt, NBV+1);
  k_hist<<<EV/256, 256, 0, stream>>>(dstA, dcnt);
  k_scan1<<<256, 256, 0, stream>>>(dcnt, rp, bsum);
  k_scan2<<<1, 256, 0, stream>>>(bsum);
  k_scan3<<<256, 256, 0, stream>>>(rp, dcnt, bsum);
  k_zero_i<<<(NBV+256)/256, 256, 0, stream>>>(dcnt, NBV+1);
  k_scatter<<<EV/256, 256, 0, stream>>>(srcA, dstA, rp, dcnt, csr_src, csr_eid);
  k_ve<<<1, 32, 0, stream>>>(g_we, g_ae, sml+20);
  k_ale<<<EV/256, 256, 0, stream>>>(ea, sml+20, ALE);

  // ---- block 1: SAGE -> TopK(410) -> gap  (X0 = input x, out F1) ----
  k_invnorm<<<1, 128, 0, stream>>>(p1_w, sml);
  k_sage_agg<<<(NBV*32)/256, 256, 0, stream>>>(x, nmask, rp, csr_src, AGG);
  k_gemm<<<NBV/64, 256, 0, stream>>>(AGG, x, c1_wl, c1_wr, c1_bl, F1, 1, 1, 1);
  k_score1<<<NBV/256, 256, 0, stream>>>(F1, p1_w, sml, sA);
  k_pool<<<BV, 512, 0, stream>>>(sA, nmask, sel, K1V);
  k_scale_gap<<<BV, 128, 0, stream>>>(F1, sel, x1g, 1.f/(float)K1V);

  // ---- block 2: SAGE -> SAGPool(205) -> gap  (F1 -> F2) ----
  k_sage_agg<<<(NBV*32)/256, 256, 0, stream>>>(F1, nmask, rp, csr_src, AGG);
  k_gemm<<<NBV/64, 256, 0, stream>>>(AGG, F1, c2_wl, c2_wr, c2_bl, F2, 1, 1, 1);
  k_qr<<<NBV/256, 256, 0, stream>>>(F2, p2_wrel, p2_wroot, qv, rv);
  k_gconv<<<NBV/256, 256, 0, stream>>>(qv, rv, nmask, rp, csr_src, p2_brel, sA);
  k_pool<<<BV, 512, 0, stream>>>(sA, nmask, sel, K2V);
  k_scale_gap<<<BV, 128, 0, stream>>>(F2, sel, x2g, 1.f/(float)K2V);

  // ---- block 3: GAT -> SAGPool(103) -> gap  (F2 -> xs=AGG -> F1) ----
  k_gemm<<<NBV/64, 256, 0, stream>>>(F2, F2, g_w, g_w, g_b, AGG, 0, 0, 0);  // xs = F2 @ g_w
  k_heads<<<(NBV*4)/256, 256, 0, stream>>>(AGG, g_as, g_ad, alS, alD);
  k_ea_part<<<256, 256, 0, stream>>>(ea, srcA, dstA, nmask, part);
  k_ea_final<<<1, 64, 0, stream>>>(part, sml+8);
  k_alse<<<1, 64, 0, stream>>>(sml+8, sml+20, sml+16);
  k_gat<<<(NBV*4)/256, 256, 0, stream>>>(AGG, alS, alD, ALE, nmask, rp, csr_src, csr_eid, sml+16, g_b, F1);
  k_qr<<<NBV/256, 256, 0, stream>>>(F1, p3_wrel, p3_wroot, qv, rv);
  k_gconv<<<NBV/256, 256, 0, stream>>>(qv, rv, nmask, rp, csr_src, p3_brel, sA);
  k_pool<<<BV, 512, 0, stream>>>(sA, nmask, sel, K3V);
  k_scale_gap<<<BV, 128, 0, stream>>>(F1, sel, x3g, 1.f/(float)K3V);

  // ---- readout MLP ----
  k_mlp<<<BV, 128, 0, stream>>>(x1g, x2g, x3g, l1_w, l1_b, l2_w, l2_b, l3_w, l3_b, out);
}

// Round 9
// 884.779 us; speedup vs baseline: 1.7319x; 1.2736x over previous
//
#include <hip/hip_runtime.h>
#include <math.h>

#define NBV 65536
#define EV  1048576
#define BV  128
#define K1V 410
#define K2V 205
#define K3V 103
#define NEG_BIG (-1.0e38f)

__device__ __forceinline__ float lrelu(float x){ return x > 0.f ? x : 0.2f*x; }

// ---------------- diagnostics sentinel ----------------
__global__ void k_sentinel(float* out, float v){
  int i = threadIdx.x;
  if (i < 128) out[i] = v;
}

// ---------------- utility ----------------
__global__ void k_fill1(float* p, int n){
  int i = blockIdx.x*blockDim.x + threadIdx.x;
  if (i < n) p[i] = 1.f;
}

__global__ void k_zero_i(int* p, int n){
  int i = blockIdx.x*blockDim.x + threadIdx.x;
  if (i < n) p[i] = 0;
}

// ---------------- CSR build (int atomics only) ----------------
__global__ void k_hist(const int* dst, int* dcnt){
  int e = blockIdx.x*blockDim.x + threadIdx.x;
  if (e < EV) atomicAdd(&dcnt[dst[e]], 1);
}

__global__ void k_scan1(const int* dcnt, int* rp, int* bsum){
  __shared__ int sc[256];
  int t = threadIdx.x, i = blockIdx.x*256 + t;
  int v = dcnt[i];
  sc[t] = v; __syncthreads();
  for (int o = 1; o < 256; o <<= 1){
    int x = (t >= o) ? sc[t-o] : 0;
    __syncthreads();
    sc[t] += x;
    __syncthreads();
  }
  rp[i] = sc[t];
  if (t == 255) bsum[blockIdx.x] = sc[t];
}

__global__ void k_scan2(int* bsum){
  __shared__ int sc[256];
  int t = threadIdx.x;
  int v = bsum[t];
  sc[t] = v; __syncthreads();
  for (int o = 1; o < 256; o <<= 1){
    int x = (t >= o) ? sc[t-o] : 0;
    __syncthreads();
    sc[t] += x;
    __syncthreads();
  }
  bsum[t] = sc[t] - v;
}

__global__ void k_scan3(int* rp, const int* dcnt, const int* bsum){
  int t = threadIdx.x, i = blockIdx.x*256 + t;
  rp[i] = rp[i] - dcnt[i] + bsum[blockIdx.x];
  if (i == 0) rp[NBV] = EV;
}

__global__ void k_scatter(const int* src, const int* dst, const int* rp, int* fill,
                          int* csr_src, int* csr_eid){
  int e = blockIdx.x*blockDim.x + threadIdx.x;
  if (e < EV){
    int d = dst[e];
    int pos = atomicAdd(&fill[d], 1);
    int slot = rp[d] + pos;
    csr_src[slot] = src[e];
    csr_eid[slot] = e;
  }
}

// ---------------- small precomputes ----------------
__global__ void k_invnorm(const float* wv, float* outv){
  __shared__ float sc[128];
  int t = threadIdx.x;
  float v = wv[t];
  sc[t] = v*v; __syncthreads();
  for (int o = 64; o > 0; o >>= 1){ if (t < o) sc[t] += sc[t+o]; __syncthreads(); }
  if (t == 0) outv[0] = 1.f / sqrtf(sc[0]);
}

__global__ void k_ve(const float* g_we, const float* g_ae, float* ve){
  int t = threadIdx.x;
  if (t < 28){
    int ed = t >> 2, h = t & 3;
    float a = 0.f;
    for (int c = 0; c < 32; c++) a += g_we[ed*128 + h*32 + c] * g_ae[h*32 + c];
    ve[t] = a;
  }
}

__global__ void k_ale(const float* ea, const float* ve, float* ALE){
  int e = blockIdx.x*blockDim.x + threadIdx.x;
  if (e < EV){
    float a0=0.f,a1=0.f,a2=0.f,a3=0.f;
    for (int ed = 0; ed < 7; ed++){
      float x = ea[e*7 + ed];
      a0 += x*ve[ed*4+0]; a1 += x*ve[ed*4+1]; a2 += x*ve[ed*4+2]; a3 += x*ve[ed*4+3];
    }
    float4 o; o.x=a0; o.y=a1; o.z=a2; o.w=a3;
    *(float4*)&ALE[(size_t)e*4] = o;
  }
}

// ---------------- SAGE mean aggregation (f32, float4) ----------------
__global__ void __launch_bounds__(256) k_sage_agg(const float* X, const float* nmask,
    const int* rp, const int* csr_src, float* AGG){
  int gid = blockIdx.x*256 + threadIdx.x;   // NBV*32 threads: (node, c4)
  int i = gid >> 5, c4 = gid & 31;
  float ax=0.f,ay=0.f,az=0.f,aw=0.f,cnt=0.f;
  if (nmask[i] > 0.f){
    int r0 = rp[i], r1 = rp[i+1];
    for (int s = r0; s < r1; s++){
      int sn = csr_src[s];
      if (nmask[sn] > 0.f){
        const float4 v = *(const float4*)&X[((size_t)sn << 7) + (c4 << 2)];
        ax += v.x; ay += v.y; az += v.z; aw += v.w; cnt += 1.f;
      }
    }
  }
  float inv = 1.f / fmaxf(cnt, 1.f);
  float4 o; o.x = ax*inv; o.y = ay*inv; o.z = az*inv; o.w = aw*inv;
  *(float4*)&AGG[((size_t)i << 7) + (c4 << 2)] = o;
}

// ---------------- dual GEMM f32, W-resident-in-LDS ----------------
// 512 threads, 128x128 tile. W (128x128) loaded to LDS ONCE per matrix;
// dual product = two sequential k-passes reusing the same W buffer.
// LDS = 64KB (W) + 8.5KB (A chunk) -> 2 blocks/CU, grid 512 fully resident.
__global__ void __launch_bounds__(512) k_gemm(const float* A1, const float* A2,
    const float* W1, const float* W2, const float* bias,
    float* OUT, int has2, int relu, int hasb){
  __shared__ float ws[128][128];   // current W, [k][j]
  __shared__ float as[16][136];    // A chunk, [k][row]
  int t = threadIdx.x;
  int n0 = blockIdx.x * 128;
  int rowg = t >> 5;               // 0..15
  int colg = t & 31;               // 0..31
  int rb = rowg * 8;
  int jb = colg * 4;
  float acc[8][4];
  for (int r = 0; r < 8; r++)
    for (int j = 0; j < 4; j++) acc[r][j] = 0.f;
  int nmat = has2 ? 2 : 1;
  for (int m = 0; m < nmat; m++){
    const float* A = (m == 0) ? A1 : A2;
    const float* W = (m == 0) ? W1 : W2;
    __syncthreads();   // all reads of previous ws complete
    // load W: 4096 float4 / 512 threads = 8 each (coalesced)
    for (int ii = 0; ii < 8; ii++){
      int idx4 = t + 512*ii;
      int kk = idx4 >> 5;
      int jj = (idx4 & 31) << 2;
      *(float4*)&ws[kk][jj] = *(const float4*)&W[kk*128 + jj];
    }
    for (int kc = 0; kc < 128; kc += 16){
      __syncthreads();   // previous chunk reads done (also orders W writes on kc==0)
      for (int ii = 0; ii < 4; ii++){
        int idx = t + 512*ii;       // 2048 = 128 rows x 16 k
        int n = idx >> 4, kk = idx & 15;
        as[kk][n] = A[((size_t)(n0+n) << 7) + kc + kk];
      }
      __syncthreads();
      for (int kk = 0; kk < 16; kk++){
        float4 wv = *(const float4*)&ws[kc+kk][jb];
        float4 aL = *(const float4*)&as[kk][rb];
        float4 aH = *(const float4*)&as[kk][rb+4];
        float a0=aL.x,a1=aL.y,a2=aL.z,a3=aL.w,a4=aH.x,a5=aH.y,a6=aH.z,a7=aH.w;
        acc[0][0]+=a0*wv.x; acc[0][1]+=a0*wv.y; acc[0][2]+=a0*wv.z; acc[0][3]+=a0*wv.w;
        acc[1][0]+=a1*wv.x; acc[1][1]+=a1*wv.y; acc[1][2]+=a1*wv.z; acc[1][3]+=a1*wv.w;
        acc[2][0]+=a2*wv.x; acc[2][1]+=a2*wv.y; acc[2][2]+=a2*wv.z; acc[2][3]+=a2*wv.w;
        acc[3][0]+=a3*wv.x; acc[3][1]+=a3*wv.y; acc[3][2]+=a3*wv.z; acc[3][3]+=a3*wv.w;
        acc[4][0]+=a4*wv.x; acc[4][1]+=a4*wv.y; acc[4][2]+=a4*wv.z; acc[4][3]+=a4*wv.w;
        acc[5][0]+=a5*wv.x; acc[5][1]+=a5*wv.y; acc[5][2]+=a5*wv.z; acc[5][3]+=a5*wv.w;
        acc[6][0]+=a6*wv.x; acc[6][1]+=a6*wv.y; acc[6][2]+=a6*wv.z; acc[6][3]+=a6*wv.w;
        acc[7][0]+=a7*wv.x; acc[7][1]+=a7*wv.y; acc[7][2]+=a7*wv.z; acc[7][3]+=a7*wv.w;
      }
    }
  }
  float bj0=0.f,bj1=0.f,bj2=0.f,bj3=0.f;
  if (hasb){
    bj0 = bias[jb+0]; bj1 = bias[jb+1]; bj2 = bias[jb+2]; bj3 = bias[jb+3];
  }
  for (int r = 0; r < 8; r++){
    float4 o;
    o.x = acc[r][0]+bj0; o.y = acc[r][1]+bj1; o.z = acc[r][2]+bj2; o.w = acc[r][3]+bj3;
    if (relu){
      o.x = fmaxf(o.x,0.f); o.y = fmaxf(o.y,0.f); o.z = fmaxf(o.z,0.f); o.w = fmaxf(o.w,0.f);
    }
    *(float4*)&OUT[((size_t)(n0+rb+r) << 7) + jb] = o;
  }
}

// ---------------- scores ----------------
__global__ void k_score1(const float* X, const float* pw, const float* invn, float* s){
  int i = blockIdx.x*blockDim.x + threadIdx.x;
  if (i >= NBV) return;
  float a = 0.f;
  const float4* x4 = (const float4*)&X[(size_t)i << 7];
  for (int c4 = 0; c4 < 32; c4++){
    float4 v = x4[c4];
    a += v.x*pw[c4*4] + v.y*pw[c4*4+1] + v.z*pw[c4*4+2] + v.w*pw[c4*4+3];
  }
  s[i] = tanhf(a * invn[0]);
}

__global__ void k_qr(const float* X, const float* wrel, const float* wroot, float* q, float* r){
  int i = blockIdx.x*blockDim.x + threadIdx.x;
  if (i >= NBV) return;
  float aq = 0.f, ar = 0.f;
  const float4* x4 = (const float4*)&X[(size_t)i << 7];
  for (int c4 = 0; c4 < 32; c4++){
    float4 v = x4[c4];
    aq += v.x*wrel[c4*4] + v.y*wrel[c4*4+1] + v.z*wrel[c4*4+2] + v.w*wrel[c4*4+3];
    ar += v.x*wroot[c4*4] + v.y*wroot[c4*4+1] + v.z*wroot[c4*4+2] + v.w*wroot[c4*4+3];
  }
  q[i] = aq; r[i] = ar;
}

__global__ void k_gconv(const float* q, const float* r, const float* nmask,
    const int* rp, const int* csr_src, const float* brel, float* s){
  int i = blockIdx.x*blockDim.x + threadIdx.x;
  if (i >= NBV) return;
  float acc = 0.f;
  if (nmask[i] > 0.f){
    int r0 = rp[i], r1 = rp[i+1];
    for (int t2 = r0; t2 < r1; t2++){
      int sn = csr_src[t2];
      if (nmask[sn] > 0.f) acc += q[sn];
    }
  }
  s[i] = tanhf(acc + brel[0] + r[i]);
}

// ---------------- top-k pool (stable tie-break == jax.lax.top_k) ----------------
__global__ void __launch_bounds__(512) k_pool(const float* s, float* nmask, float* sel, int K){
  __shared__ float sc[512];
  int b = blockIdx.x, t = threadIdx.x;
  int i = b*512 + t;
  float nm = nmask[i];
  float sv = s[i];
  float ms = (nm > 0.f) ? sv : NEG_BIG;
  sc[t] = ms;
  __syncthreads();
  int rank = 0;
  for (int j = 0; j < 512; j++){
    float o = sc[j];
    rank += ((o > ms) || (o == ms && j < t)) ? 1 : 0;
  }
  bool selb = rank < K;
  nmask[i] = selb ? 1.f : 0.f;
  sel[i] = selb ? sv : 0.f;
}

// scale kept rows by score (in place) + gap partials — no atomics, 1024 blocks.
__global__ void __launch_bounds__(128) k_scale_part(float* X, const float* sel, float* part){
  int b = blockIdx.x >> 3, q = blockIdx.x & 7, c = threadIdx.x;
  float acc = 0.f;
  for (int n = q*64; n < q*64 + 64; n++){
    int i = b*512 + n;
    float v = X[((size_t)i << 7) + c] * sel[i];
    X[((size_t)i << 7) + c] = v;
    acc += v;
  }
  part[(size_t)blockIdx.x*128 + c] = acc;
}

__global__ void __launch_bounds__(128) k_gap_final(const float* part, float* gap, float invK){
  int b = blockIdx.x, c = threadIdx.x;
  float s = 0.f;
  for (int q = 0; q < 8; q++) s += part[(size_t)(b*8+q)*128 + c];
  gap[b*128 + c] = s * invK;
}

// ---------------- GAT pieces ----------------
__global__ void k_heads(const float* xs, const float* a_s, const float* a_d,
                        float* alS, float* alD){
  int gid = blockIdx.x*blockDim.x + threadIdx.x;
  int i = gid >> 2, h = gid & 3;
  if (i >= NBV) return;
  float as_ = 0.f, ad_ = 0.f;
  for (int c = 0; c < 32; c++){
    float v = xs[((size_t)i << 7) + h*32 + c];
    as_ += v * a_s[h*32 + c];
    ad_ += v * a_d[h*32 + c];
  }
  alS[gid] = as_; alD[gid] = ad_;
}

// edge-attr masked mean: per-block partials (no atomics)
__global__ void __launch_bounds__(256) k_ea_part(const float* ea, const int* srcA, const int* dstA,
    const float* nmask, float* part){
  float p[8] = {0.f,0.f,0.f,0.f,0.f,0.f,0.f,0.f};
  for (int e = blockIdx.x*256 + threadIdx.x; e < EV; e += 256*256){
    if (nmask[srcA[e]] > 0.f && nmask[dstA[e]] > 0.f){
      for (int d = 0; d < 7; d++) p[d] += ea[e*7 + d];
      p[7] += 1.f;
    }
  }
  __shared__ float red[256];
  for (int comp = 0; comp < 8; comp++){
    red[threadIdx.x] = p[comp]; __syncthreads();
    for (int o = 128; o > 0; o >>= 1){ if (threadIdx.x < o) red[threadIdx.x] += red[threadIdx.x + o]; __syncthreads(); }
    if (threadIdx.x == 0) part[blockIdx.x*8 + comp] = red[0];
    __syncthreads();
  }
}

__global__ void k_ea_final(const float* part, float* easum){
  int h = threadIdx.x;
  if (h < 8){
    float s = 0.f;
    for (int b = 0; b < 256; b++) s += part[b*8 + h];
    easum[h] = s;
  }
}

__global__ void k_alse(const float* easum, const float* ve, float* alse){
  if (threadIdx.x == 0 && blockIdx.x == 0){
    float cnt = fmaxf(easum[7], 1.f);
    for (int h = 0; h < 4; h++){
      float s = 0.f;
      for (int ed = 0; ed < 7; ed++) s += (easum[ed]/cnt) * ve[ed*4 + h];
      alse[h] = s;
    }
  }
}

__global__ void __launch_bounds__(256) k_gat(const float* xs, const float* alS, const float* alD,
    const float* ALE, const float* nmask, const int* rp, const int* csr_src,
    const int* csr_eid, const float* alse, const float* g_b, float* OUT){
  int gid = blockIdx.x*256 + threadIdx.x;
  int i = gid >> 2, h = gid & 3;
  float nmi = nmask[i];
  float ald_i = alD[i*4 + h];
  float als_i = alS[i*4 + h];
  float aself = (nmi > 0.f) ? lrelu(als_i + ald_i + alse[h]) : NEG_BIG;
  float m = aself;
  int r0 = rp[i], r1 = rp[i+1];
  const float4* xs4 = (const float4*)xs;
  if (nmi > 0.f){
    for (int t2 = r0; t2 < r1; t2++){
      int sn = csr_src[t2];
      if (nmask[sn] > 0.f){
        float a = lrelu(alS[sn*4 + h] + ald_i + ALE[(size_t)csr_eid[t2]*4 + h]);
        m = fmaxf(m, a);
      }
    }
  }
  if (m < -1.0e37f) m = 0.f;   // matches jnp.where(isfinite(m), m, 0)
  float den = 0.f;
  float4 acc[8];
  for (int c4 = 0; c4 < 8; c4++){ acc[c4].x=0.f; acc[c4].y=0.f; acc[c4].z=0.f; acc[c4].w=0.f; }
  if (nmi > 0.f){
    float es = expf(aself - m);
    den = es;
    for (int c4 = 0; c4 < 8; c4++){
      float4 v = xs4[(size_t)i*32 + h*8 + c4];
      acc[c4].x = es*v.x; acc[c4].y = es*v.y; acc[c4].z = es*v.z; acc[c4].w = es*v.w;
    }
    for (int t2 = r0; t2 < r1; t2++){
      int sn = csr_src[t2];
      if (nmask[sn] > 0.f){
        float a = lrelu(alS[sn*4 + h] + ald_i + ALE[(size_t)csr_eid[t2]*4 + h]);
        float ex = expf(a - m);
        den += ex;
        for (int c4 = 0; c4 < 8; c4++){
          float4 v = xs4[(size_t)sn*32 + h*8 + c4];
          acc[c4].x += ex*v.x; acc[c4].y += ex*v.y; acc[c4].z += ex*v.z; acc[c4].w += ex*v.w;
        }
      }
    }
  }
  den = fmaxf(den, 1e-16f);
  float rd = 1.f/den;
  for (int c4 = 0; c4 < 8; c4++){
    int cb = h*32 + c4*4;
    float4 o;
    o.x = fmaxf(acc[c4].x*rd + g_b[cb+0], 0.f);
    o.y = fmaxf(acc[c4].y*rd + g_b[cb+1], 0.f);
    o.z = fmaxf(acc[c4].z*rd + g_b[cb+2], 0.f);
    o.w = fmaxf(acc[c4].w*rd + g_b[cb+3], 0.f);
    *(float4*)&OUT[((size_t)i << 7) + cb] = o;
  }
}

// ---------------- final MLP ----------------
__global__ void __launch_bounds__(128) k_mlp(const float* x1g, const float* x2g, const float* x3g,
    const float* l1w, const float* l1b, const float* l2w, const float* l2b,
    const float* l3w, const float* l3b, float* out){
  __shared__ float hh[128];
  __shared__ float h2[128];
  __shared__ float h3[64];
  int b = blockIdx.x, t = threadIdx.x;
  hh[t] = x1g[b*128 + t] + x2g[b*128 + t] + x3g[b*128 + t];
  __syncthreads();
  float a = l1b[t];
  for (int k = 0; k < 128; k++) a += hh[k] * l1w[k*128 + t];
  h2[t] = fmaxf(a, 0.f);
  __syncthreads();
  if (t < 64){
    float a2 = l2b[t];
    for (int k = 0; k < 128; k++) a2 += h2[k] * l2w[k*64 + t];
    h3[t] = fmaxf(a2, 0.f);
  }
  __syncthreads();
  if (t == 0){
    float z = l3b[0];
    for (int k = 0; k < 64; k++) z += h3[k] * l3w[k];
    out[b] = 1.f/(1.f + expf(-z));
  }
}

// ---------------- launch ----------------
extern "C" void kernel_launch(void* const* d_in, const int* in_sizes, int n_in,
                              void* d_out, int out_size, void* d_ws, size_t ws_size,
                              hipStream_t stream){
  const float* x       = (const float*)d_in[0];
  const int*   ei      = (const int*)d_in[1];
  const float* ea      = (const float*)d_in[2];
  const float* c1_wl   = (const float*)d_in[3];
  const float* c1_bl   = (const float*)d_in[4];
  const float* c1_wr   = (const float*)d_in[5];
  const float* p1_w    = (const float*)d_in[6];
  const float* c2_wl   = (const float*)d_in[7];
  const float* c2_bl   = (const float*)d_in[8];
  const float* c2_wr   = (const float*)d_in[9];
  const float* p2_wrel = (const float*)d_in[10];
  const float* p2_brel = (const float*)d_in[11];
  const float* p2_wroot= (const float*)d_in[12];
  const float* g_w     = (const float*)d_in[13];
  const float* g_as    = (const float*)d_in[14];
  const float* g_ad    = (const float*)d_in[15];
  const float* g_we    = (const float*)d_in[16];
  const float* g_ae    = (const float*)d_in[17];
  const float* g_b     = (const float*)d_in[18];
  const float* p3_wrel = (const float*)d_in[19];
  const float* p3_brel = (const float*)d_in[20];
  const float* p3_wroot= (const float*)d_in[21];
  const float* l1_w    = (const float*)d_in[22];
  const float* l1_b    = (const float*)d_in[23];
  const float* l2_w    = (const float*)d_in[24];
  const float* l2_b    = (const float*)d_in[25];
  const float* l3_w    = (const float*)d_in[26];
  const float* l3_b    = (const float*)d_in[27];
  float* out = (float*)d_out;
  (void)in_sizes; (void)n_in; (void)out_size;

  // Workspace layout (f32, ~137 MB)
  char* w = (char*)d_ws;
  size_t off = 0;
  float* AGG  = (float*)(w + off); off += (size_t)NBV*128*4;
  float* F1   = (float*)(w + off); off += (size_t)NBV*128*4;
  float* F2   = (float*)(w + off); off += (size_t)NBV*128*4;
  float* ALE  = (float*)(w + off); off += (size_t)EV*4*4;
  float* sA   = (float*)(w + off); off += (size_t)NBV*4;
  float* sel  = (float*)(w + off); off += (size_t)NBV*4;
  float* qv   = (float*)(w + off); off += (size_t)NBV*4;
  float* rv   = (float*)(w + off); off += (size_t)NBV*4;
  float* nmask= (float*)(w + off); off += (size_t)NBV*4;
  float* alS  = (float*)(w + off); off += (size_t)NBV*4*4;
  float* alD  = (float*)(w + off); off += (size_t)NBV*4*4;
  float* x1g  = (float*)(w + off); off += (size_t)BV*128*4;
  float* x2g  = (float*)(w + off); off += (size_t)BV*128*4;
  float* x3g  = (float*)(w + off); off += (size_t)BV*128*4;
  float* sml  = (float*)(w + off); off += 64*4;      // [0]=invnorm [8..15]=easum [16..19]=alse [20..47]=ve
  float* eprt = (float*)(w + off); off += 2048*4;    // ea partials
  float* gprt = (float*)(w + off); off += (size_t)1024*128*4;  // gap partials
  int* csr_src = (int*)(w + off); off += (size_t)EV*4;
  int* csr_eid = (int*)(w + off); off += (size_t)EV*4;
  int* rp      = (int*)(w + off); off += (size_t)(NBV+64)*4;
  int* dcnt    = (int*)(w + off); off += (size_t)(NBV+64)*4;
  int* bsum    = (int*)(w + off); off += 1024;
  size_t needed = off;

  float sentinel = (ws_size >= needed) ? 0.125f : 0.875f;
  k_sentinel<<<1, 128, 0, stream>>>(out, sentinel);

  const int* srcA = ei;
  const int* dstA = ei + EV;

  // ---- setup ----
  k_fill1<<<NBV/256, 256, 0, stream>>>(nmask, NBV);
  k_zero_i<<<(NBV+256)/256, 256, 0, stream>>>(dcnt, NBV+1);
  k_hist<<<EV/256, 256, 0, stream>>>(dstA, dcnt);
  k_scan1<<<256, 256, 0, stream>>>(dcnt, rp, bsum);
  k_scan2<<<1, 256, 0, stream>>>(bsum);
  k_scan3<<<256, 256, 0, stream>>>(rp, dcnt, bsum);
  k_zero_i<<<(NBV+256)/256, 256, 0, stream>>>(dcnt, NBV+1);
  k_scatter<<<EV/256, 256, 0, stream>>>(srcA, dstA, rp, dcnt, csr_src, csr_eid);
  k_ve<<<1, 32, 0, stream>>>(g_we, g_ae, sml+20);
  k_ale<<<EV/256, 256, 0, stream>>>(ea, sml+20, ALE);

  // ---- block 1: SAGE -> TopK(410) -> gap  (x -> F1) ----
  k_invnorm<<<1, 128, 0, stream>>>(p1_w, sml);
  k_sage_agg<<<(NBV*32)/256, 256, 0, stream>>>(x, nmask, rp, csr_src, AGG);
  k_gemm<<<NBV/128, 512, 0, stream>>>(AGG, x, c1_wl, c1_wr, c1_bl, F1, 1, 1, 1);
  k_score1<<<NBV/256, 256, 0, stream>>>(F1, p1_w, sml, sA);
  k_pool<<<BV, 512, 0, stream>>>(sA, nmask, sel, K1V);
  k_scale_part<<<BV*8, 128, 0, stream>>>(F1, sel, gprt);
  k_gap_final<<<BV, 128, 0, stream>>>(gprt, x1g, 1.f/(float)K1V);

  // ---- block 2: SAGE -> SAGPool(205) -> gap  (F1 -> F2) ----
  k_sage_agg<<<(NBV*32)/256, 256, 0, stream>>>(F1, nmask, rp, csr_src, AGG);
  k_gemm<<<NBV/128, 512, 0, stream>>>(AGG, F1, c2_wl, c2_wr, c2_bl, F2, 1, 1, 1);
  k_qr<<<NBV/256, 256, 0, stream>>>(F2, p2_wrel, p2_wroot, qv, rv);
  k_gconv<<<NBV/256, 256, 0, stream>>>(qv, rv, nmask, rp, csr_src, p2_brel, sA);
  k_pool<<<BV, 512, 0, stream>>>(sA, nmask, sel, K2V);
  k_scale_part<<<BV*8, 128, 0, stream>>>(F2, sel, gprt);
  k_gap_final<<<BV, 128, 0, stream>>>(gprt, x2g, 1.f/(float)K2V);

  // ---- block 3: GAT -> SAGPool(103) -> gap  (F2 -> xs=AGG -> F1) ----
  k_gemm<<<NBV/128, 512, 0, stream>>>(F2, F2, g_w, g_w, g_b, AGG, 0, 0, 0);  // xs = F2 @ g_w
  k_heads<<<(NBV*4)/256, 256, 0, stream>>>(AGG, g_as, g_ad, alS, alD);
  k_ea_part<<<256, 256, 0, stream>>>(ea, srcA, dstA, nmask, eprt);
  k_ea_final<<<1, 64, 0, stream>>>(eprt, sml+8);
  k_alse<<<1, 64, 0, stream>>>(sml+8, sml+20, sml+16);
  k_gat<<<(NBV*4)/256, 256, 0, stream>>>(AGG, alS, alD, ALE, nmask, rp, csr_src, csr_eid, sml+16, g_b, F1);
  k_qr<<<NBV/256, 256, 0, stream>>>(F1, p3_wrel, p3_wroot, qv, rv);
  k_gconv<<<NBV/256, 256, 0, stream>>>(qv, rv, nmask, rp, csr_src, p3_brel, sA);
  k_pool<<<BV, 512, 0, stream>>>(sA, nmask, sel, K3V);
  k_scale_part<<<BV*8, 128, 0, stream>>>(F1, sel, gprt);
  k_gap_final<<<BV, 128, 0, stream>>>(gprt, x3g, 1.f/(float)K3V);

  // ---- readout MLP ----
  k_mlp<<<BV, 128, 0, stream>>>(x1g, x2g, x3g, l1_w, l1_b, l2_w, l2_b, l3_w, l3_b, out);
}

// Round 10
// 803.032 us; speedup vs baseline: 1.9082x; 1.1018x over previous
//
#include <hip/hip_runtime.h>
#include <math.h>

#define NBV 65536
#define EV  1048576
#define BV  128
#define K1V 410
#define K2V 205
#define K3V 103
#define NEG_BIG (-1.0e38f)

__device__ __forceinline__ float lrelu(float x){ return x > 0.f ? x : 0.2f*x; }

// ---------------- diagnostics sentinel ----------------
__global__ void k_sentinel(float* out, float v){
  int i = threadIdx.x;
  if (i < 128) out[i] = v;
}

// ---------------- utility ----------------
__global__ void k_fill1(float* p, int n){
  int i = blockIdx.x*blockDim.x + threadIdx.x;
  if (i < n) p[i] = 1.f;
}

__global__ void k_zero_i(int* p, int n){
  int i = blockIdx.x*blockDim.x + threadIdx.x;
  if (i < n) p[i] = 0;
}

// ---------------- CSR build (int atomics only) ----------------
__global__ void k_hist(const int* dst, int* dcnt){
  int e = blockIdx.x*blockDim.x + threadIdx.x;
  if (e < EV) atomicAdd(&dcnt[dst[e]], 1);
}

__global__ void k_scan1(const int* dcnt, int* rp, int* bsum){
  __shared__ int sc[256];
  int t = threadIdx.x, i = blockIdx.x*256 + t;
  int v = dcnt[i];
  sc[t] = v; __syncthreads();
  for (int o = 1; o < 256; o <<= 1){
    int x = (t >= o) ? sc[t-o] : 0;
    __syncthreads();
    sc[t] += x;
    __syncthreads();
  }
  rp[i] = sc[t];
  if (t == 255) bsum[blockIdx.x] = sc[t];
}

__global__ void k_scan2(int* bsum){
  __shared__ int sc[256];
  int t = threadIdx.x;
  int v = bsum[t];
  sc[t] = v; __syncthreads();
  for (int o = 1; o < 256; o <<= 1){
    int x = (t >= o) ? sc[t-o] : 0;
    __syncthreads();
    sc[t] += x;
    __syncthreads();
  }
  bsum[t] = sc[t] - v;
}

__global__ void k_scan3(int* rp, const int* dcnt, const int* bsum){
  int t = threadIdx.x, i = blockIdx.x*256 + t;
  rp[i] = rp[i] - dcnt[i] + bsum[blockIdx.x];
  if (i == 0) rp[NBV] = EV;
}

__global__ void k_scatter(const int* src, const int* dst, const int* rp, int* fill,
                          int* csr_src, int* csr_eid){
  int e = blockIdx.x*blockDim.x + threadIdx.x;
  if (e < EV){
    int d = dst[e];
    int pos = atomicAdd(&fill[d], 1);
    int slot = rp[d] + pos;
    csr_src[slot] = src[e];
    csr_eid[slot] = e;
  }
}

// ---------------- small precomputes ----------------
__global__ void k_invnorm(const float* wv, float* outv){
  __shared__ float sc[128];
  int t = threadIdx.x;
  float v = wv[t];
  sc[t] = v*v; __syncthreads();
  for (int o = 64; o > 0; o >>= 1){ if (t < o) sc[t] += sc[t+o]; __syncthreads(); }
  if (t == 0) outv[0] = 1.f / sqrtf(sc[0]);
}

__global__ void k_ve(const float* g_we, const float* g_ae, float* ve){
  int t = threadIdx.x;
  if (t < 28){
    int ed = t >> 2, h = t & 3;
    float a = 0.f;
    for (int c = 0; c < 32; c++) a += g_we[ed*128 + h*32 + c] * g_ae[h*32 + c];
    ve[t] = a;
  }
}

__global__ void k_ale(const float* ea, const float* ve, float* ALE){
  int e = blockIdx.x*blockDim.x + threadIdx.x;
  if (e < EV){
    float a0=0.f,a1=0.f,a2=0.f,a3=0.f;
    for (int ed = 0; ed < 7; ed++){
      float x = ea[e*7 + ed];
      a0 += x*ve[ed*4+0]; a1 += x*ve[ed*4+1]; a2 += x*ve[ed*4+2]; a3 += x*ve[ed*4+3];
    }
    float4 o; o.x=a0; o.y=a1; o.z=a2; o.w=a3;
    *(float4*)&ALE[(size_t)e*4] = o;
  }
}

// ---------------- SAGE mean aggregation (f32, float4, idx-prefetch) ----------------
__global__ void __launch_bounds__(256) k_sage_agg(const float* X, const float* nmask,
    const int* rp, const int* csr_src, float* AGG){
  int gid = blockIdx.x*256 + threadIdx.x;   // NBV*32 threads: (node, c4)
  int i = gid >> 5, c4 = gid & 31;
  float ax=0.f,ay=0.f,az=0.f,aw=0.f,cnt=0.f;
  if (nmask[i] > 0.f){
    int r0 = rp[i], r1 = rp[i+1];
    int sn_n = 0; float nm_n = 0.f;
    if (r0 < r1){ sn_n = csr_src[r0]; nm_n = nmask[sn_n]; }
    for (int s = r0; s < r1; s++){
      int sn = sn_n; float nm = nm_n;
      if (s+1 < r1){ sn_n = csr_src[s+1]; nm_n = nmask[sn_n]; }
      if (nm > 0.f){
        const float4 v = *(const float4*)&X[((size_t)sn << 7) + (c4 << 2)];
        ax += v.x; ay += v.y; az += v.z; aw += v.w; cnt += 1.f;
      }
    }
  }
  float inv = 1.f / fmaxf(cnt, 1.f);
  float4 o; o.x = ax*inv; o.y = ay*inv; o.z = az*inv; o.w = aw*inv;
  *(float4*)&AGG[((size_t)i << 7) + (c4 << 2)] = o;
}

// ---------------- dual GEMM f32, W-resident-in-LDS ----------------
__global__ void __launch_bounds__(512) k_gemm(const float* A1, const float* A2,
    const float* W1, const float* W2, const float* bias,
    float* OUT, int has2, int relu, int hasb){
  __shared__ float ws[128][128];
  __shared__ float as[16][136];
  int t = threadIdx.x;
  int n0 = blockIdx.x * 128;
  int rowg = t >> 5;
  int colg = t & 31;
  int rb = rowg * 8;
  int jb = colg * 4;
  float acc[8][4];
  for (int r = 0; r < 8; r++)
    for (int j = 0; j < 4; j++) acc[r][j] = 0.f;
  int nmat = has2 ? 2 : 1;
  for (int m = 0; m < nmat; m++){
    const float* A = (m == 0) ? A1 : A2;
    const float* W = (m == 0) ? W1 : W2;
    __syncthreads();
    for (int ii = 0; ii < 8; ii++){
      int idx4 = t + 512*ii;
      int kk = idx4 >> 5;
      int jj = (idx4 & 31) << 2;
      *(float4*)&ws[kk][jj] = *(const float4*)&W[kk*128 + jj];
    }
    for (int kc = 0; kc < 128; kc += 16){
      __syncthreads();
      for (int ii = 0; ii < 4; ii++){
        int idx = t + 512*ii;
        int n = idx >> 4, kk = idx & 15;
        as[kk][n] = A[((size_t)(n0+n) << 7) + kc + kk];
      }
      __syncthreads();
      for (int kk = 0; kk < 16; kk++){
        float4 wv = *(const float4*)&ws[kc+kk][jb];
        float4 aL = *(const float4*)&as[kk][rb];
        float4 aH = *(const float4*)&as[kk][rb+4];
        float a0=aL.x,a1=aL.y,a2=aL.z,a3=aL.w,a4=aH.x,a5=aH.y,a6=aH.z,a7=aH.w;
        acc[0][0]+=a0*wv.x; acc[0][1]+=a0*wv.y; acc[0][2]+=a0*wv.z; acc[0][3]+=a0*wv.w;
        acc[1][0]+=a1*wv.x; acc[1][1]+=a1*wv.y; acc[1][2]+=a1*wv.z; acc[1][3]+=a1*wv.w;
        acc[2][0]+=a2*wv.x; acc[2][1]+=a2*wv.y; acc[2][2]+=a2*wv.z; acc[2][3]+=a2*wv.w;
        acc[3][0]+=a3*wv.x; acc[3][1]+=a3*wv.y; acc[3][2]+=a3*wv.z; acc[3][3]+=a3*wv.w;
        acc[4][0]+=a4*wv.x; acc[4][1]+=a4*wv.y; acc[4][2]+=a4*wv.z; acc[4][3]+=a4*wv.w;
        acc[5][0]+=a5*wv.x; acc[5][1]+=a5*wv.y; acc[5][2]+=a5*wv.z; acc[5][3]+=a5*wv.w;
        acc[6][0]+=a6*wv.x; acc[6][1]+=a6*wv.y; acc[6][2]+=a6*wv.z; acc[6][3]+=a6*wv.w;
        acc[7][0]+=a7*wv.x; acc[7][1]+=a7*wv.y; acc[7][2]+=a7*wv.z; acc[7][3]+=a7*wv.w;
      }
    }
  }
  float bj0=0.f,bj1=0.f,bj2=0.f,bj3=0.f;
  if (hasb){
    bj0 = bias[jb+0]; bj1 = bias[jb+1]; bj2 = bias[jb+2]; bj3 = bias[jb+3];
  }
  for (int r = 0; r < 8; r++){
    float4 o;
    o.x = acc[r][0]+bj0; o.y = acc[r][1]+bj1; o.z = acc[r][2]+bj2; o.w = acc[r][3]+bj3;
    if (relu){
      o.x = fmaxf(o.x,0.f); o.y = fmaxf(o.y,0.f); o.z = fmaxf(o.z,0.f); o.w = fmaxf(o.w,0.f);
    }
    *(float4*)&OUT[((size_t)(n0+rb+r) << 7) + jb] = o;
  }
}

// ---------------- scores (32 lanes/node, shfl reduce) ----------------
__global__ void __launch_bounds__(256) k_score1(const float* X, const float* pw, const float* invn, float* s){
  int gid = blockIdx.x*256 + threadIdx.x;   // NBV*32
  int i = gid >> 5, c4 = gid & 31;
  float4 v = *(const float4*)&X[((size_t)i << 7) + (c4 << 2)];
  float4 wv = *(const float4*)&pw[c4 << 2];
  float a = v.x*wv.x + v.y*wv.y + v.z*wv.z + v.w*wv.w;
  for (int o = 16; o > 0; o >>= 1) a += __shfl_down(a, o, 32);
  if (c4 == 0) s[i] = tanhf(a * invn[0]);
}

__global__ void __launch_bounds__(256) k_qr(const float* X, const float* wrel, const float* wroot,
                                            float* q, float* r){
  int gid = blockIdx.x*256 + threadIdx.x;   // NBV*32
  int i = gid >> 5, c4 = gid & 31;
  float4 v = *(const float4*)&X[((size_t)i << 7) + (c4 << 2)];
  float4 wa = *(const float4*)&wrel[c4 << 2];
  float4 wb = *(const float4*)&wroot[c4 << 2];
  float aq = v.x*wa.x + v.y*wa.y + v.z*wa.z + v.w*wa.w;
  float ar = v.x*wb.x + v.y*wb.y + v.z*wb.z + v.w*wb.w;
  for (int o = 16; o > 0; o >>= 1){
    aq += __shfl_down(aq, o, 32);
    ar += __shfl_down(ar, o, 32);
  }
  if (c4 == 0){ q[i] = aq; r[i] = ar; }
}

__global__ void k_gconv(const float* q, const float* r, const float* nmask,
    const int* rp, const int* csr_src, const float* brel, float* s){
  int i = blockIdx.x*blockDim.x + threadIdx.x;
  if (i >= NBV) return;
  float acc = 0.f;
  if (nmask[i] > 0.f){
    int r0 = rp[i], r1 = rp[i+1];
    int sn_n = 0; float nm_n = 0.f;
    if (r0 < r1){ sn_n = csr_src[r0]; nm_n = nmask[sn_n]; }
    for (int t2 = r0; t2 < r1; t2++){
      int sn = sn_n; float nm = nm_n;
      if (t2+1 < r1){ sn_n = csr_src[t2+1]; nm_n = nmask[sn_n]; }
      if (nm > 0.f) acc += q[sn];
    }
  }
  s[i] = tanhf(acc + brel[0] + r[i]);
}

// ---------------- top-k pool (stable tie-break == jax.lax.top_k) ----------------
__global__ void __launch_bounds__(512) k_pool(const float* s, float* nmask, float* sel, int K){
  __shared__ float sc[512];
  int b = blockIdx.x, t = threadIdx.x;
  int i = b*512 + t;
  float nm = nmask[i];
  float sv = s[i];
  float ms = (nm > 0.f) ? sv : NEG_BIG;
  sc[t] = ms;
  __syncthreads();
  int rank = 0;
  for (int j = 0; j < 512; j++){
    float o = sc[j];
    rank += ((o > ms) || (o == ms && j < t)) ? 1 : 0;
  }
  bool selb = rank < K;
  nmask[i] = selb ? 1.f : 0.f;
  sel[i] = selb ? sv : 0.f;
}

// scale kept rows by score (in place) + gap partials — no atomics.
__global__ void __launch_bounds__(128) k_scale_part(float* X, const float* sel, float* part){
  int b = blockIdx.x >> 3, q = blockIdx.x & 7, c = threadIdx.x;
  float acc = 0.f;
  for (int n = q*64; n < q*64 + 64; n++){
    int i = b*512 + n;
    float v = X[((size_t)i << 7) + c] * sel[i];
    X[((size_t)i << 7) + c] = v;
    acc += v;
  }
  part[(size_t)blockIdx.x*128 + c] = acc;
}

__global__ void __launch_bounds__(128) k_gap_final(const float* part, float* gap, float invK){
  int b = blockIdx.x, c = threadIdx.x;
  float s = 0.f;
  for (int q = 0; q < 8; q++) s += part[(size_t)(b*8+q)*128 + c];
  gap[b*128 + c] = s * invK;
}

// ---------------- GAT pieces ----------------
__global__ void k_heads(const float* xs, const float* a_s, const float* a_d,
                        float* alS, float* alD){
  int gid = blockIdx.x*blockDim.x + threadIdx.x;   // NBV*4
  int i = gid >> 2, h = gid & 3;
  if (i >= NBV) return;
  const float4* xr = (const float4*)&xs[((size_t)i << 7) + h*32];
  const float4* wa = (const float4*)&a_s[h*32];
  const float4* wd = (const float4*)&a_d[h*32];
  float as_ = 0.f, ad_ = 0.f;
  for (int c4 = 0; c4 < 8; c4++){
    float4 v = xr[c4]; float4 A = wa[c4]; float4 D = wd[c4];
    as_ += v.x*A.x + v.y*A.y + v.z*A.z + v.w*A.w;
    ad_ += v.x*D.x + v.y*D.y + v.z*D.z + v.w*D.w;
  }
  alS[gid] = as_; alD[gid] = ad_;
}

// edge-attr masked mean: per-block partials (no atomics)
__global__ void __launch_bounds__(256) k_ea_part(const float* ea, const int* srcA, const int* dstA,
    const float* nmask, float* part){
  float p[8] = {0.f,0.f,0.f,0.f,0.f,0.f,0.f,0.f};
  for (int e = blockIdx.x*256 + threadIdx.x; e < EV; e += 256*256){
    if (nmask[srcA[e]] > 0.f && nmask[dstA[e]] > 0.f){
      for (int d = 0; d < 7; d++) p[d] += ea[e*7 + d];
      p[7] += 1.f;
    }
  }
  __shared__ float red[256];
  for (int comp = 0; comp < 8; comp++){
    red[threadIdx.x] = p[comp]; __syncthreads();
    for (int o = 128; o > 0; o >>= 1){ if (threadIdx.x < o) red[threadIdx.x] += red[threadIdx.x + o]; __syncthreads(); }
    if (threadIdx.x == 0) part[blockIdx.x*8 + comp] = red[0];
    __syncthreads();
  }
}

__global__ void k_ea_final(const float* part, float* easum){
  int h = threadIdx.x;
  if (h < 8){
    float s = 0.f;
    for (int b = 0; b < 256; b++) s += part[b*8 + h];
    easum[h] = s;
  }
}

__global__ void k_alse(const float* easum, const float* ve, float* alse){
  if (threadIdx.x == 0 && blockIdx.x == 0){
    float cnt = fmaxf(easum[7], 1.f);
    for (int h = 0; h < 4; h++){
      float s = 0.f;
      for (int ed = 0; ed < 7; ed++) s += (easum[ed]/cnt) * ve[ed*4 + h];
      alse[h] = s;
    }
  }
}

// GAT: 32 threads/node (8 per head, one float4 each), single-pass online softmax.
__global__ void __launch_bounds__(256) k_gat(const float* xs, const float* alS, const float* alD,
    const float* ALE, const float* nmask, const int* rp, const int* csr_src,
    const int* csr_eid, const float* alse, const float* g_b, float* OUT){
  int gid = blockIdx.x*256 + threadIdx.x;   // NBV*32
  int i = gid >> 5;
  int lane = gid & 31;
  int h = lane >> 3;
  int cidx = h*8 + (lane & 7);              // float4 index within 128-wide row
  float nmi = nmask[i];
  const float4* xs4 = (const float4*)xs;
  float m = 0.f, den = 0.f;
  float4 acc; acc.x=0.f; acc.y=0.f; acc.z=0.f; acc.w=0.f;
  if (nmi > 0.f){
    float ald_i = alD[i*4 + h];
    m = lrelu(alS[i*4 + h] + ald_i + alse[h]);   // aself
    den = 1.f;
    acc = xs4[(size_t)i*32 + cidx];
    int r0 = rp[i], r1 = rp[i+1];
    int sn_n = 0, eid_n = 0; float nm_n = 0.f;
    if (r0 < r1){ sn_n = csr_src[r0]; eid_n = csr_eid[r0]; nm_n = nmask[sn_n]; }
    for (int t2 = r0; t2 < r1; t2++){
      int sn = sn_n, eid = eid_n; float nm = nm_n;
      if (t2+1 < r1){ sn_n = csr_src[t2+1]; eid_n = csr_eid[t2+1]; nm_n = nmask[sn_n]; }
      if (nm > 0.f){
        float a = lrelu(alS[sn*4 + h] + ald_i + ALE[(size_t)eid*4 + h]);
        float4 v = xs4[(size_t)sn*32 + cidx];
        float mn = fmaxf(m, a);
        float pm = expf(m - mn);
        float pa = expf(a - mn);
        den = den*pm + pa;
        acc.x = acc.x*pm + pa*v.x;
        acc.y = acc.y*pm + pa*v.y;
        acc.z = acc.z*pm + pa*v.z;
        acc.w = acc.w*pm + pa*v.w;
        m = mn;
      }
    }
  }
  den = fmaxf(den, 1e-16f);
  float rd = 1.f/den;
  int cb = cidx << 2;
  float4 o;
  o.x = fmaxf(acc.x*rd + g_b[cb+0], 0.f);
  o.y = fmaxf(acc.y*rd + g_b[cb+1], 0.f);
  o.z = fmaxf(acc.z*rd + g_b[cb+2], 0.f);
  o.w = fmaxf(acc.w*rd + g_b[cb+3], 0.f);
  *(float4*)&OUT[((size_t)i << 7) + cb] = o;
}

// ---------------- final MLP ----------------
__global__ void __launch_bounds__(128) k_mlp(const float* x1g, const float* x2g, const float* x3g,
    const float* l1w, const float* l1b, const float* l2w, const float* l2b,
    const float* l3w, const float* l3b, float* out){
  __shared__ float hh[128];
  __shared__ float h2[128];
  __shared__ float h3[64];
  int b = blockIdx.x, t = threadIdx.x;
  hh[t] = x1g[b*128 + t] + x2g[b*128 + t] + x3g[b*128 + t];
  __syncthreads();
  float a = l1b[t];
  for (int k = 0; k < 128; k++) a += hh[k] * l1w[k*128 + t];
  h2[t] = fmaxf(a, 0.f);
  __syncthreads();
  if (t < 64){
    float a2 = l2b[t];
    for (int k = 0; k < 128; k++) a2 += h2[k] * l2w[k*64 + t];
    h3[t] = fmaxf(a2, 0.f);
  }
  __syncthreads();
  if (t == 0){
    float z = l3b[0];
    for (int k = 0; k < 64; k++) z += h3[k] * l3w[k];
    out[b] = 1.f/(1.f + expf(-z));
  }
}

// ---------------- launch ----------------
extern "C" void kernel_launch(void* const* d_in, const int* in_sizes, int n_in,
                              void* d_out, int out_size, void* d_ws, size_t ws_size,
                              hipStream_t stream){
  const float* x       = (const float*)d_in[0];
  const int*   ei      = (const int*)d_in[1];
  const float* ea      = (const float*)d_in[2];
  const float* c1_wl   = (const float*)d_in[3];
  const float* c1_bl   = (const float*)d_in[4];
  const float* c1_wr   = (const float*)d_in[5];
  const float* p1_w    = (const float*)d_in[6];
  const float* c2_wl   = (const float*)d_in[7];
  const float* c2_bl   = (const float*)d_in[8];
  const float* c2_wr   = (const float*)d_in[9];
  const float* p2_wrel = (const float*)d_in[10];
  const float* p2_brel = (const float*)d_in[11];
  const float* p2_wroot= (const float*)d_in[12];
  const float* g_w     = (const float*)d_in[13];
  const float* g_as    = (const float*)d_in[14];
  const float* g_ad    = (const float*)d_in[15];
  const float* g_we    = (const float*)d_in[16];
  const float* g_ae    = (const float*)d_in[17];
  const float* g_b     = (const float*)d_in[18];
  const float* p3_wrel = (const float*)d_in[19];
  const float* p3_brel = (const float*)d_in[20];
  const float* p3_wroot= (const float*)d_in[21];
  const float* l1_w    = (const float*)d_in[22];
  const float* l1_b    = (const float*)d_in[23];
  const float* l2_w    = (const float*)d_in[24];
  const float* l2_b    = (const float*)d_in[25];
  const float* l3_w    = (const float*)d_in[26];
  const float* l3_b    = (const float*)d_in[27];
  float* out = (float*)d_out;
  (void)in_sizes; (void)n_in; (void)out_size;

  // Workspace layout (f32, ~137 MB)
  char* w = (char*)d_ws;
  size_t off = 0;
  float* AGG  = (float*)(w + off); off += (size_t)NBV*128*4;
  float* F1   = (float*)(w + off); off += (size_t)NBV*128*4;
  float* F2   = (float*)(w + off); off += (size_t)NBV*128*4;
  float* ALE  = (float*)(w + off); off += (size_t)EV*4*4;
  float* sA   = (float*)(w + off); off += (size_t)NBV*4;
  float* sel  = (float*)(w + off); off += (size_t)NBV*4;
  float* qv   = (float*)(w + off); off += (size_t)NBV*4;
  float* rv   = (float*)(w + off); off += (size_t)NBV*4;
  float* nmask= (float*)(w + off); off += (size_t)NBV*4;
  float* alS  = (float*)(w + off); off += (size_t)NBV*4*4;
  float* alD  = (float*)(w + off); off += (size_t)NBV*4*4;
  float* x1g  = (float*)(w + off); off += (size_t)BV*128*4;
  float* x2g  = (float*)(w + off); off += (size_t)BV*128*4;
  float* x3g  = (float*)(w + off); off += (size_t)BV*128*4;
  float* sml  = (float*)(w + off); off += 64*4;      // [0]=invnorm [8..15]=easum [16..19]=alse [20..47]=ve
  float* eprt = (float*)(w + off); off += 2048*4;
  float* gprt = (float*)(w + off); off += (size_t)1024*128*4;
  int* csr_src = (int*)(w + off); off += (size_t)EV*4;
  int* csr_eid = (int*)(w + off); off += (size_t)EV*4;
  int* rp      = (int*)(w + off); off += (size_t)(NBV+64)*4;
  int* dcnt    = (int*)(w + off); off += (size_t)(NBV+64)*4;
  int* bsum    = (int*)(w + off); off += 1024;
  size_t needed = off;

  float sentinel = (ws_size >= needed) ? 0.125f : 0.875f;
  k_sentinel<<<1, 128, 0, stream>>>(out, sentinel);

  const int* srcA = ei;
  const int* dstA = ei + EV;

  // ---- setup ----
  k_fill1<<<NBV/256, 256, 0, stream>>>(nmask, NBV);
  k_zero_i<<<(NBV+256)/256, 256, 0, stream>>>(dcnt, NBV+1);
  k_hist<<<EV/256, 256, 0, stream>>>(dstA, dcnt);
  k_scan1<<<256, 256, 0, stream>>>(dcnt, rp, bsum);
  k_scan2<<<1, 256, 0, stream>>>(bsum);
  k_scan3<<<256, 256, 0, stream>>>(rp, dcnt, bsum);
  k_zero_i<<<(NBV+256)/256, 256, 0, stream>>>(dcnt, NBV+1);
  k_scatter<<<EV/256, 256, 0, stream>>>(srcA, dstA, rp, dcnt, csr_src, csr_eid);
  k_ve<<<1, 32, 0, stream>>>(g_we, g_ae, sml+20);
  k_ale<<<EV/256, 256, 0, stream>>>(ea, sml+20, ALE);

  // ---- block 1: SAGE -> TopK(410) -> gap  (x -> F1) ----
  k_invnorm<<<1, 128, 0, stream>>>(p1_w, sml);
  k_sage_agg<<<(NBV*32)/256, 256, 0, stream>>>(x, nmask, rp, csr_src, AGG);
  k_gemm<<<NBV/128, 512, 0, stream>>>(AGG, x, c1_wl, c1_wr, c1_bl, F1, 1, 1, 1);
  k_score1<<<(NBV*32)/256, 256, 0, stream>>>(F1, p1_w, sml, sA);
  k_pool<<<BV, 512, 0, stream>>>(sA, nmask, sel, K1V);
  k_scale_part<<<BV*8, 128, 0, stream>>>(F1, sel, gprt);
  k_gap_final<<<BV, 128, 0, stream>>>(gprt, x1g, 1.f/(float)K1V);

  // ---- block 2: SAGE -> SAGPool(205) -> gap  (F1 -> F2) ----
  k_sage_agg<<<(NBV*32)/256, 256, 0, stream>>>(F1, nmask, rp, csr_src, AGG);
  k_gemm<<<NBV/128, 512, 0, stream>>>(AGG, F1, c2_wl, c2_wr, c2_bl, F2, 1, 1, 1);
  k_qr<<<(NBV*32)/256, 256, 0, stream>>>(F2, p2_wrel, p2_wroot, qv, rv);
  k_gconv<<<NBV/256, 256, 0, stream>>>(qv, rv, nmask, rp, csr_src, p2_brel, sA);
  k_pool<<<BV, 512, 0, stream>>>(sA, nmask, sel, K2V);
  k_scale_part<<<BV*8, 128, 0, stream>>>(F2, sel, gprt);
  k_gap_final<<<BV, 128, 0, stream>>>(gprt, x2g, 1.f/(float)K2V);

  // ---- block 3: GAT -> SAGPool(103) -> gap  (F2 -> xs=AGG -> F1) ----
  k_gemm<<<NBV/128, 512, 0, stream>>>(F2, F2, g_w, g_w, g_b, AGG, 0, 0, 0);  // xs = F2 @ g_w
  k_heads<<<(NBV*4)/256, 256, 0, stream>>>(AGG, g_as, g_ad, alS, alD);
  k_ea_part<<<256, 256, 0, stream>>>(ea, srcA, dstA, nmask, eprt);
  k_ea_final<<<1, 64, 0, stream>>>(eprt, sml+8);
  k_alse<<<1, 64, 0, stream>>>(sml+8, sml+20, sml+16);
  k_gat<<<(NBV*32)/256, 256, 0, stream>>>(AGG, alS, alD, ALE, nmask, rp, csr_src, csr_eid, sml+16, g_b, F1);
  k_qr<<<(NBV*32)/256, 256, 0, stream>>>(F1, p3_wrel, p3_wroot, qv, rv);
  k_gconv<<<NBV/256, 256, 0, stream>>>(qv, rv, nmask, rp, csr_src, p3_brel, sA);
  k_pool<<<BV, 512, 0, stream>>>(sA, nmask, sel, K3V);
  k_scale_part<<<BV*8, 128, 0, stream>>>(F1, sel, gprt);
  k_gap_final<<<BV, 128, 0, stream>>>(gprt, x3g, 1.f/(float)K3V);

  // ---- readout MLP ----
  k_mlp<<<BV, 128, 0, stream>>>(x1g, x2g, x3g, l1_w, l1_b, l2_w, l2_b, l3_w, l3_b, out);
}

// Round 11
// 723.361 us; speedup vs baseline: 2.1183x; 1.1101x over previous
//
#include <hip/hip_runtime.h>
#include <math.h>

#define NBV 65536
#define EV  1048576
#define BV  128
#define K1V 410
#define K2V 205
#define K3V 103
#define NEG_BIG (-1.0e38f)

__device__ __forceinline__ float lrelu(float x){ return x > 0.f ? x : 0.2f*x; }

// ---------------- diagnostics sentinel ----------------
__global__ void k_sentinel(float* out, float v){
  int i = threadIdx.x;
  if (i < 128) out[i] = v;
}

// ---------------- utility ----------------
__global__ void k_fill1(float* p, int n){
  int i = blockIdx.x*blockDim.x + threadIdx.x;
  if (i < n) p[i] = 1.f;
}

__global__ void k_zero_i(int* p, int n){
  int i = blockIdx.x*blockDim.x + threadIdx.x;
  if (i < n) p[i] = 0;
}

// ---------------- CSR build (int atomics only) ----------------
__global__ void k_hist(const int* dst, int* dcnt){
  int e = blockIdx.x*blockDim.x + threadIdx.x;
  if (e < EV) atomicAdd(&dcnt[dst[e]], 1);
}

__global__ void k_scan1(const int* dcnt, int* rp, int* bsum){
  __shared__ int sc[256];
  int t = threadIdx.x, i = blockIdx.x*256 + t;
  int v = dcnt[i];
  sc[t] = v; __syncthreads();
  for (int o = 1; o < 256; o <<= 1){
    int x = (t >= o) ? sc[t-o] : 0;
    __syncthreads();
    sc[t] += x;
    __syncthreads();
  }
  rp[i] = sc[t];
  if (t == 255) bsum[blockIdx.x] = sc[t];
}

__global__ void k_scan2(int* bsum){
  __shared__ int sc[256];
  int t = threadIdx.x;
  int v = bsum[t];
  sc[t] = v; __syncthreads();
  for (int o = 1; o < 256; o <<= 1){
    int x = (t >= o) ? sc[t-o] : 0;
    __syncthreads();
    sc[t] += x;
    __syncthreads();
  }
  bsum[t] = sc[t] - v;
}

__global__ void k_scan3(int* rp, const int* dcnt, const int* bsum){
  int t = threadIdx.x, i = blockIdx.x*256 + t;
  rp[i] = rp[i] - dcnt[i] + bsum[blockIdx.x];
  if (i == 0) rp[NBV] = EV;
}

__global__ void k_scatter(const int* src, const int* dst, const int* rp, int* fill,
                          int* csr_src, int* csr_eid){
  int e = blockIdx.x*blockDim.x + threadIdx.x;
  if (e < EV){
    int d = dst[e];
    int pos = atomicAdd(&fill[d], 1);
    int slot = rp[d] + pos;
    csr_src[slot] = src[e];
    csr_eid[slot] = e;
  }
}

// ---------------- small precomputes ----------------
__global__ void k_invnorm(const float* wv, float* outv){
  __shared__ float sc[128];
  int t = threadIdx.x;
  float v = wv[t];
  sc[t] = v*v; __syncthreads();
  for (int o = 64; o > 0; o >>= 1){ if (t < o) sc[t] += sc[t+o]; __syncthreads(); }
  if (t == 0) outv[0] = 1.f / sqrtf(sc[0]);
}

__global__ void k_ve(const float* g_we, const float* g_ae, float* ve){
  int t = threadIdx.x;
  if (t < 28){
    int ed = t >> 2, h = t & 3;
    float a = 0.f;
    for (int c = 0; c < 32; c++) a += g_we[ed*128 + h*32 + c] * g_ae[h*32 + c];
    ve[t] = a;
  }
}

__global__ void k_ale(const float* ea, const float* ve, float* ALE){
  int e = blockIdx.x*blockDim.x + threadIdx.x;
  if (e < EV){
    float a0=0.f,a1=0.f,a2=0.f,a3=0.f;
    for (int ed = 0; ed < 7; ed++){
      float x = ea[e*7 + ed];
      a0 += x*ve[ed*4+0]; a1 += x*ve[ed*4+1]; a2 += x*ve[ed*4+2]; a3 += x*ve[ed*4+3];
    }
    float4 o; o.x=a0; o.y=a1; o.z=a2; o.w=a3;
    *(float4*)&ALE[(size_t)e*4] = o;
  }
}

// ---------------- SAGE mean aggregation (XCD-swizzled, 4-deep gather) ----------------
// 8192 blocks; graph = blockIdx%128 so all 64 blocks of a graph land on one XCD
// (XCD = blockIdx%8): 16 graphs x 256KB slice = 4MB = one L2.
__global__ void __launch_bounds__(256) k_sage_agg(const float* X, const float* nmask,
    const int* rp, const int* csr_src, float* AGG, int masked){
  int g = blockIdx.x & 127;
  int blk = blockIdx.x >> 7;
  int i = g*512 + blk*8 + (threadIdx.x >> 5);
  int c4 = threadIdx.x & 31;
  float ax=0.f,ay=0.f,az=0.f,aw=0.f,cnt=0.f;
  if (!masked || nmask[i] > 0.f){
    int r0 = rp[i], r1 = rp[i+1];
    int s = r0;
    for (; s + 4 <= r1; s += 4){
      int sn0 = csr_src[s+0], sn1 = csr_src[s+1], sn2 = csr_src[s+2], sn3 = csr_src[s+3];
      float4 v0 = *(const float4*)&X[((size_t)sn0 << 7) + (c4 << 2)];
      float4 v1 = *(const float4*)&X[((size_t)sn1 << 7) + (c4 << 2)];
      float4 v2 = *(const float4*)&X[((size_t)sn2 << 7) + (c4 << 2)];
      float4 v3 = *(const float4*)&X[((size_t)sn3 << 7) + (c4 << 2)];
      float nm0 = masked ? nmask[sn0] : 1.f;
      float nm1 = masked ? nmask[sn1] : 1.f;
      float nm2 = masked ? nmask[sn2] : 1.f;
      float nm3 = masked ? nmask[sn3] : 1.f;
      if (nm0 > 0.f){ ax += v0.x; ay += v0.y; az += v0.z; aw += v0.w; cnt += 1.f; }
      if (nm1 > 0.f){ ax += v1.x; ay += v1.y; az += v1.z; aw += v1.w; cnt += 1.f; }
      if (nm2 > 0.f){ ax += v2.x; ay += v2.y; az += v2.z; aw += v2.w; cnt += 1.f; }
      if (nm3 > 0.f){ ax += v3.x; ay += v3.y; az += v3.z; aw += v3.w; cnt += 1.f; }
    }
    for (; s < r1; s++){
      int sn = csr_src[s];
      float nm = masked ? nmask[sn] : 1.f;
      if (nm > 0.f){
        const float4 v = *(const float4*)&X[((size_t)sn << 7) + (c4 << 2)];
        ax += v.x; ay += v.y; az += v.z; aw += v.w; cnt += 1.f;
      }
    }
  }
  float inv = 1.f / fmaxf(cnt, 1.f);
  float4 o; o.x = ax*inv; o.y = ay*inv; o.z = az*inv; o.w = aw*inv;
  *(float4*)&AGG[((size_t)i << 7) + (c4 << 2)] = o;
}

// ---------------- dual GEMM f32, W-resident-in-LDS ----------------
__global__ void __launch_bounds__(512) k_gemm(const float* A1, const float* A2,
    const float* W1, const float* W2, const float* bias,
    float* OUT, int has2, int relu, int hasb){
  __shared__ float ws[128][128];
  __shared__ float as[16][136];
  int t = threadIdx.x;
  int n0 = blockIdx.x * 128;
  int rowg = t >> 5;
  int colg = t & 31;
  int rb = rowg * 8;
  int jb = colg * 4;
  float acc[8][4];
  for (int r = 0; r < 8; r++)
    for (int j = 0; j < 4; j++) acc[r][j] = 0.f;
  int nmat = has2 ? 2 : 1;
  for (int m = 0; m < nmat; m++){
    const float* A = (m == 0) ? A1 : A2;
    const float* W = (m == 0) ? W1 : W2;
    __syncthreads();
    for (int ii = 0; ii < 8; ii++){
      int idx4 = t + 512*ii;
      int kk = idx4 >> 5;
      int jj = (idx4 & 31) << 2;
      *(float4*)&ws[kk][jj] = *(const float4*)&W[kk*128 + jj];
    }
    for (int kc = 0; kc < 128; kc += 16){
      __syncthreads();
      for (int ii = 0; ii < 4; ii++){
        int idx = t + 512*ii;
        int n = idx >> 4, kk = idx & 15;
        as[kk][n] = A[((size_t)(n0+n) << 7) + kc + kk];
      }
      __syncthreads();
      for (int kk = 0; kk < 16; kk++){
        float4 wv = *(const float4*)&ws[kc+kk][jb];
        float4 aL = *(const float4*)&as[kk][rb];
        float4 aH = *(const float4*)&as[kk][rb+4];
        float a0=aL.x,a1=aL.y,a2=aL.z,a3=aL.w,a4=aH.x,a5=aH.y,a6=aH.z,a7=aH.w;
        acc[0][0]+=a0*wv.x; acc[0][1]+=a0*wv.y; acc[0][2]+=a0*wv.z; acc[0][3]+=a0*wv.w;
        acc[1][0]+=a1*wv.x; acc[1][1]+=a1*wv.y; acc[1][2]+=a1*wv.z; acc[1][3]+=a1*wv.w;
        acc[2][0]+=a2*wv.x; acc[2][1]+=a2*wv.y; acc[2][2]+=a2*wv.z; acc[2][3]+=a2*wv.w;
        acc[3][0]+=a3*wv.x; acc[3][1]+=a3*wv.y; acc[3][2]+=a3*wv.z; acc[3][3]+=a3*wv.w;
        acc[4][0]+=a4*wv.x; acc[4][1]+=a4*wv.y; acc[4][2]+=a4*wv.z; acc[4][3]+=a4*wv.w;
        acc[5][0]+=a5*wv.x; acc[5][1]+=a5*wv.y; acc[5][2]+=a5*wv.z; acc[5][3]+=a5*wv.w;
        acc[6][0]+=a6*wv.x; acc[6][1]+=a6*wv.y; acc[6][2]+=a6*wv.z; acc[6][3]+=a6*wv.w;
        acc[7][0]+=a7*wv.x; acc[7][1]+=a7*wv.y; acc[7][2]+=a7*wv.z; acc[7][3]+=a7*wv.w;
      }
    }
  }
  float bj0=0.f,bj1=0.f,bj2=0.f,bj3=0.f;
  if (hasb){
    bj0 = bias[jb+0]; bj1 = bias[jb+1]; bj2 = bias[jb+2]; bj3 = bias[jb+3];
  }
  for (int r = 0; r < 8; r++){
    float4 o;
    o.x = acc[r][0]+bj0; o.y = acc[r][1]+bj1; o.z = acc[r][2]+bj2; o.w = acc[r][3]+bj3;
    if (relu){
      o.x = fmaxf(o.x,0.f); o.y = fmaxf(o.y,0.f); o.z = fmaxf(o.z,0.f); o.w = fmaxf(o.w,0.f);
    }
    *(float4*)&OUT[((size_t)(n0+rb+r) << 7) + jb] = o;
  }
}

// ---------------- scores (32 lanes/node, shfl reduce) ----------------
__global__ void __launch_bounds__(256) k_score1(const float* X, const float* pw, const float* invn, float* s){
  int gid = blockIdx.x*256 + threadIdx.x;
  int i = gid >> 5, c4 = gid & 31;
  float4 v = *(const float4*)&X[((size_t)i << 7) + (c4 << 2)];
  float4 wv = *(const float4*)&pw[c4 << 2];
  float a = v.x*wv.x + v.y*wv.y + v.z*wv.z + v.w*wv.w;
  for (int o = 16; o > 0; o >>= 1) a += __shfl_down(a, o, 32);
  if (c4 == 0) s[i] = tanhf(a * invn[0]);
}

__global__ void __launch_bounds__(256) k_qr(const float* X, const float* wrel, const float* wroot,
                                            float* q, float* r){
  int gid = blockIdx.x*256 + threadIdx.x;
  int i = gid >> 5, c4 = gid & 31;
  float4 v = *(const float4*)&X[((size_t)i << 7) + (c4 << 2)];
  float4 wa = *(const float4*)&wrel[c4 << 2];
  float4 wb = *(const float4*)&wroot[c4 << 2];
  float aq = v.x*wa.x + v.y*wa.y + v.z*wa.z + v.w*wa.w;
  float ar = v.x*wb.x + v.y*wb.y + v.z*wb.z + v.w*wb.w;
  for (int o = 16; o > 0; o >>= 1){
    aq += __shfl_down(aq, o, 32);
    ar += __shfl_down(ar, o, 32);
  }
  if (c4 == 0){ q[i] = aq; r[i] = ar; }
}

__global__ void k_gconv(const float* q, const float* r, const float* nmask,
    const int* rp, const int* csr_src, const float* brel, float* s){
  int i = blockIdx.x*blockDim.x + threadIdx.x;
  if (i >= NBV) return;
  float acc = 0.f;
  if (nmask[i] > 0.f){
    int r0 = rp[i], r1 = rp[i+1];
    int t2 = r0;
    for (; t2 + 4 <= r1; t2 += 4){
      int sn0 = csr_src[t2+0], sn1 = csr_src[t2+1], sn2 = csr_src[t2+2], sn3 = csr_src[t2+3];
      float nm0 = nmask[sn0], nm1 = nmask[sn1], nm2 = nmask[sn2], nm3 = nmask[sn3];
      float q0 = q[sn0], q1 = q[sn1], q2 = q[sn2], q3 = q[sn3];
      if (nm0 > 0.f) acc += q0;
      if (nm1 > 0.f) acc += q1;
      if (nm2 > 0.f) acc += q2;
      if (nm3 > 0.f) acc += q3;
    }
    for (; t2 < r1; t2++){
      int sn = csr_src[t2];
      if (nmask[sn] > 0.f) acc += q[sn];
    }
  }
  s[i] = tanhf(acc + brel[0] + r[i]);
}

// ---------------- top-k pool (stable tie-break == jax.lax.top_k) ----------------
__global__ void __launch_bounds__(512) k_pool(const float* s, float* nmask, float* sel, int K){
  __shared__ float sc[512];
  int b = blockIdx.x, t = threadIdx.x;
  int i = b*512 + t;
  float nm = nmask[i];
  float sv = s[i];
  float ms = (nm > 0.f) ? sv : NEG_BIG;
  sc[t] = ms;
  __syncthreads();
  int rank = 0;
  for (int j = 0; j < 512; j++){
    float o = sc[j];
    rank += ((o > ms) || (o == ms && j < t)) ? 1 : 0;
  }
  bool selb = rank < K;
  nmask[i] = selb ? 1.f : 0.f;
  sel[i] = selb ? sv : 0.f;
}

// scale kept rows by score (in place) + gap partials — no atomics.
__global__ void __launch_bounds__(128) k_scale_part(float* X, const float* sel, float* part){
  int b = blockIdx.x >> 3, q = blockIdx.x & 7, c = threadIdx.x;
  float acc = 0.f;
  for (int n = q*64; n < q*64 + 64; n++){
    int i = b*512 + n;
    float v = X[((size_t)i << 7) + c] * sel[i];
    X[((size_t)i << 7) + c] = v;
    acc += v;
  }
  part[(size_t)blockIdx.x*128 + c] = acc;
}

__global__ void __launch_bounds__(128) k_gap_final(const float* part, float* gap, float invK){
  int b = blockIdx.x, c = threadIdx.x;
  float s = 0.f;
  for (int q = 0; q < 8; q++) s += part[(size_t)(b*8+q)*128 + c];
  gap[b*128 + c] = s * invK;
}

// ---------------- GAT pieces ----------------
__global__ void k_heads(const float* xs, const float* a_s, const float* a_d,
                        float* alS, float* alD){
  int gid = blockIdx.x*blockDim.x + threadIdx.x;
  int i = gid >> 2, h = gid & 3;
  if (i >= NBV) return;
  const float4* xr = (const float4*)&xs[((size_t)i << 7) + h*32];
  const float4* wa = (const float4*)&a_s[h*32];
  const float4* wd = (const float4*)&a_d[h*32];
  float as_ = 0.f, ad_ = 0.f;
  for (int c4 = 0; c4 < 8; c4++){
    float4 v = xr[c4]; float4 A = wa[c4]; float4 D = wd[c4];
    as_ += v.x*A.x + v.y*A.y + v.z*A.z + v.w*A.w;
    ad_ += v.x*D.x + v.y*D.y + v.z*D.z + v.w*D.w;
  }
  alS[gid] = as_; alD[gid] = ad_;
}

// edge-attr masked mean: per-block partials (no atomics)
__global__ void __launch_bounds__(256) k_ea_part(const float* ea, const int* srcA, const int* dstA,
    const float* nmask, float* part){
  float p[8] = {0.f,0.f,0.f,0.f,0.f,0.f,0.f,0.f};
  for (int e = blockIdx.x*256 + threadIdx.x; e < EV; e += 256*256){
    if (nmask[srcA[e]] > 0.f && nmask[dstA[e]] > 0.f){
      for (int d = 0; d < 7; d++) p[d] += ea[e*7 + d];
      p[7] += 1.f;
    }
  }
  __shared__ float red[256];
  for (int comp = 0; comp < 8; comp++){
    red[threadIdx.x] = p[comp]; __syncthreads();
    for (int o = 128; o > 0; o >>= 1){ if (threadIdx.x < o) red[threadIdx.x] += red[threadIdx.x + o]; __syncthreads(); }
    if (threadIdx.x == 0) part[blockIdx.x*8 + comp] = red[0];
    __syncthreads();
  }
}

__global__ void k_ea_final(const float* part, float* easum){
  int h = threadIdx.x;
  if (h < 8){
    float s = 0.f;
    for (int b = 0; b < 256; b++) s += part[b*8 + h];
    easum[h] = s;
  }
}

__global__ void k_alse(const float* easum, const float* ve, float* alse){
  if (threadIdx.x == 0 && blockIdx.x == 0){
    float cnt = fmaxf(easum[7], 1.f);
    for (int h = 0; h < 4; h++){
      float s = 0.f;
      for (int ed = 0; ed < 7; ed++) s += (easum[ed]/cnt) * ve[ed*4 + h];
      alse[h] = s;
    }
  }
}

// GAT: 32 threads/node, XCD-swizzled, 4-deep gathers + in-order online softmax.
__global__ void __launch_bounds__(256) k_gat(const float* xs, const float* alS, const float* alD,
    const float* ALE, const float* nmask, const int* rp, const int* csr_src,
    const int* csr_eid, const float* alse, const float* g_b, float* OUT){
  int g = blockIdx.x & 127;
  int blk = blockIdx.x >> 7;
  int i = g*512 + blk*8 + (threadIdx.x >> 5);
  int lane = threadIdx.x & 31;
  int h = lane >> 3;
  int cidx = h*8 + (lane & 7);
  float nmi = nmask[i];
  const float4* xs4 = (const float4*)xs;
  float m = 0.f, den = 0.f;
  float4 acc; acc.x=0.f; acc.y=0.f; acc.z=0.f; acc.w=0.f;
  if (nmi > 0.f){
    float ald_i = alD[i*4 + h];
    m = lrelu(alS[i*4 + h] + ald_i + alse[h]);   // aself
    den = 1.f;
    acc = xs4[(size_t)i*32 + cidx];
    int r0 = rp[i], r1 = rp[i+1];
    int s = r0;
    for (; s + 4 <= r1; s += 4){
      int sn0 = csr_src[s+0], sn1 = csr_src[s+1], sn2 = csr_src[s+2], sn3 = csr_src[s+3];
      int e0 = csr_eid[s+0], e1 = csr_eid[s+1], e2 = csr_eid[s+2], e3 = csr_eid[s+3];
      float nm0 = nmask[sn0], nm1 = nmask[sn1], nm2 = nmask[sn2], nm3 = nmask[sn3];
      float al0 = alS[sn0*4 + h], al1 = alS[sn1*4 + h], al2 = alS[sn2*4 + h], al3 = alS[sn3*4 + h];
      float ae0 = ALE[(size_t)e0*4 + h], ae1 = ALE[(size_t)e1*4 + h];
      float ae2 = ALE[(size_t)e2*4 + h], ae3 = ALE[(size_t)e3*4 + h];
      float4 v0 = xs4[(size_t)sn0*32 + cidx];
      float4 v1 = xs4[(size_t)sn1*32 + cidx];
      float4 v2 = xs4[(size_t)sn2*32 + cidx];
      float4 v3 = xs4[(size_t)sn3*32 + cidx];
      if (nm0 > 0.f){
        float a = lrelu(al0 + ald_i + ae0);
        float mn = fmaxf(m, a); float pm = expf(m - mn); float pa = expf(a - mn);
        den = den*pm + pa;
        acc.x = acc.x*pm + pa*v0.x; acc.y = acc.y*pm + pa*v0.y;
        acc.z = acc.z*pm + pa*v0.z; acc.w = acc.w*pm + pa*v0.w;
        m = mn;
      }
      if (nm1 > 0.f){
        float a = lrelu(al1 + ald_i + ae1);
        float mn = fmaxf(m, a); float pm = expf(m - mn); float pa = expf(a - mn);
        den = den*pm + pa;
        acc.x = acc.x*pm + pa*v1.x; acc.y = acc.y*pm + pa*v1.y;
        acc.z = acc.z*pm + pa*v1.z; acc.w = acc.w*pm + pa*v1.w;
        m = mn;
      }
      if (nm2 > 0.f){
        float a = lrelu(al2 + ald_i + ae2);
        float mn = fmaxf(m, a); float pm = expf(m - mn); float pa = expf(a - mn);
        den = den*pm + pa;
        acc.x = acc.x*pm + pa*v2.x; acc.y = acc.y*pm + pa*v2.y;
        acc.z = acc.z*pm + pa*v2.z; acc.w = acc.w*pm + pa*v2.w;
        m = mn;
      }
      if (nm3 > 0.f){
        float a = lrelu(al3 + ald_i + ae3);
        float mn = fmaxf(m, a); float pm = expf(m - mn); float pa = expf(a - mn);
        den = den*pm + pa;
        acc.x = acc.x*pm + pa*v3.x; acc.y = acc.y*pm + pa*v3.y;
        acc.z = acc.z*pm + pa*v3.z; acc.w = acc.w*pm + pa*v3.w;
        m = mn;
      }
    }
    for (; s < r1; s++){
      int sn = csr_src[s];
      if (nmask[sn] > 0.f){
        float a = lrelu(alS[sn*4 + h] + ald_i + ALE[(size_t)csr_eid[s]*4 + h]);
        float4 v = xs4[(size_t)sn*32 + cidx];
        float mn = fmaxf(m, a); float pm = expf(m - mn); float pa = expf(a - mn);
        den = den*pm + pa;
        acc.x = acc.x*pm + pa*v.x; acc.y = acc.y*pm + pa*v.y;
        acc.z = acc.z*pm + pa*v.z; acc.w = acc.w*pm + pa*v.w;
        m = mn;
      }
    }
  }
  den = fmaxf(den, 1e-16f);
  float rd = 1.f/den;
  int cb = cidx << 2;
  float4 o;
  o.x = fmaxf(acc.x*rd + g_b[cb+0], 0.f);
  o.y = fmaxf(acc.y*rd + g_b[cb+1], 0.f);
  o.z = fmaxf(acc.z*rd + g_b[cb+2], 0.f);
  o.w = fmaxf(acc.w*rd + g_b[cb+3], 0.f);
  *(float4*)&OUT[((size_t)i << 7) + cb] = o;
}

// ---------------- final MLP ----------------
__global__ void __launch_bounds__(128) k_mlp(const float* x1g, const float* x2g, const float* x3g,
    const float* l1w, const float* l1b, const float* l2w, const float* l2b,
    const float* l3w, const float* l3b, float* out){
  __shared__ float hh[128];
  __shared__ float h2[128];
  __shared__ float h3[64];
  int b = blockIdx.x, t = threadIdx.x;
  hh[t] = x1g[b*128 + t] + x2g[b*128 + t] + x3g[b*128 + t];
  __syncthreads();
  float a = l1b[t];
  for (int k = 0; k < 128; k++) a += hh[k] * l1w[k*128 + t];
  h2[t] = fmaxf(a, 0.f);
  __syncthreads();
  if (t < 64){
    float a2 = l2b[t];
    for (int k = 0; k < 128; k++) a2 += h2[k] * l2w[k*64 + t];
    h3[t] = fmaxf(a2, 0.f);
  }
  __syncthreads();
  if (t == 0){
    float z = l3b[0];
    for (int k = 0; k < 64; k++) z += h3[k] * l3w[k];
    out[b] = 1.f/(1.f + expf(-z));
  }
}

// ---------------- launch ----------------
extern "C" void kernel_launch(void* const* d_in, const int* in_sizes, int n_in,
                              void* d_out, int out_size, void* d_ws, size_t ws_size,
                              hipStream_t stream){
  const float* x       = (const float*)d_in[0];
  const int*   ei      = (const int*)d_in[1];
  const float* ea      = (const float*)d_in[2];
  const float* c1_wl   = (const float*)d_in[3];
  const float* c1_bl   = (const float*)d_in[4];
  const float* c1_wr   = (const float*)d_in[5];
  const float* p1_w    = (const float*)d_in[6];
  const float* c2_wl   = (const float*)d_in[7];
  const float* c2_bl   = (const float*)d_in[8];
  const float* c2_wr   = (const float*)d_in[9];
  const float* p2_wrel = (const float*)d_in[10];
  const float* p2_brel = (const float*)d_in[11];
  const float* p2_wroot= (const float*)d_in[12];
  const float* g_w     = (const float*)d_in[13];
  const float* g_as    = (const float*)d_in[14];
  const float* g_ad    = (const float*)d_in[15];
  const float* g_we    = (const float*)d_in[16];
  const float* g_ae    = (const float*)d_in[17];
  const float* g_b     = (const float*)d_in[18];
  const float* p3_wrel = (const float*)d_in[19];
  const float* p3_brel = (const float*)d_in[20];
  const float* p3_wroot= (const float*)d_in[21];
  const float* l1_w    = (const float*)d_in[22];
  const float* l1_b    = (const float*)d_in[23];
  const float* l2_w    = (const float*)d_in[24];
  const float* l2_b    = (const float*)d_in[25];
  const float* l3_w    = (const float*)d_in[26];
  const float* l3_b    = (const float*)d_in[27];
  float* out = (float*)d_out;
  (void)in_sizes; (void)n_in; (void)out_size;

  // Workspace layout (f32, ~137 MB)
  char* w = (char*)d_ws;
  size_t off = 0;
  float* AGG  = (float*)(w + off); off += (size_t)NBV*128*4;
  float* F1   = (float*)(w + off); off += (size_t)NBV*128*4;
  float* F2   = (float*)(w + off); off += (size_t)NBV*128*4;
  float* ALE  = (float*)(w + off); off += (size_t)EV*4*4;
  float* sA   = (float*)(w + off); off += (size_t)NBV*4;
  float* sel  = (float*)(w + off); off += (size_t)NBV*4;
  float* qv   = (float*)(w + off); off += (size_t)NBV*4;
  float* rv   = (float*)(w + off); off += (size_t)NBV*4;
  float* nmask= (float*)(w + off); off += (size_t)NBV*4;
  float* alS  = (float*)(w + off); off += (size_t)NBV*4*4;
  float* alD  = (float*)(w + off); off += (size_t)NBV*4*4;
  float* x1g  = (float*)(w + off); off += (size_t)BV*128*4;
  float* x2g  = (float*)(w + off); off += (size_t)BV*128*4;
  float* x3g  = (float*)(w + off); off += (size_t)BV*128*4;
  float* sml  = (float*)(w + off); off += 64*4;      // [0]=invnorm [8..15]=easum [16..19]=alse [20..47]=ve
  float* eprt = (float*)(w + off); off += 2048*4;
  float* gprt = (float*)(w + off); off += (size_t)1024*128*4;
  int* csr_src = (int*)(w + off); off += (size_t)EV*4;
  int* csr_eid = (int*)(w + off); off += (size_t)EV*4;
  int* rp      = (int*)(w + off); off += (size_t)(NBV+64)*4;
  int* dcnt    = (int*)(w + off); off += (size_t)(NBV+64)*4;
  int* bsum    = (int*)(w + off); off += 1024;
  size_t needed = off;

  float sentinel = (ws_size >= needed) ? 0.125f : 0.875f;
  k_sentinel<<<1, 128, 0, stream>>>(out, sentinel);

  const int* srcA = ei;
  const int* dstA = ei + EV;

  // ---- setup ----
  k_fill1<<<NBV/256, 256, 0, stream>>>(nmask, NBV);
  k_zero_i<<<(NBV+256)/256, 256, 0, stream>>>(dcnt, NBV+1);
  k_hist<<<EV/256, 256, 0, stream>>>(dstA, dcnt);
  k_scan1<<<256, 256, 0, stream>>>(dcnt, rp, bsum);
  k_scan2<<<1, 256, 0, stream>>>(bsum);
  k_scan3<<<256, 256, 0, stream>>>(rp, dcnt, bsum);
  k_zero_i<<<(NBV+256)/256, 256, 0, stream>>>(dcnt, NBV+1);
  k_scatter<<<EV/256, 256, 0, stream>>>(srcA, dstA, rp, dcnt, csr_src, csr_eid);
  k_ve<<<1, 32, 0, stream>>>(g_we, g_ae, sml+20);
  k_ale<<<EV/256, 256, 0, stream>>>(ea, sml+20, ALE);

  // ---- block 1: SAGE -> TopK(410) -> gap  (x -> F1) ----
  k_invnorm<<<1, 128, 0, stream>>>(p1_w, sml);
  k_sage_agg<<<(NBV*32)/256, 256, 0, stream>>>(x, nmask, rp, csr_src, AGG, 0);
  k_gemm<<<NBV/128, 512, 0, stream>>>(AGG, x, c1_wl, c1_wr, c1_bl, F1, 1, 1, 1);
  k_score1<<<(NBV*32)/256, 256, 0, stream>>>(F1, p1_w, sml, sA);
  k_pool<<<BV, 512, 0, stream>>>(sA, nmask, sel, K1V);
  k_scale_part<<<BV*8, 128, 0, stream>>>(F1, sel, gprt);
  k_gap_final<<<BV, 128, 0, stream>>>(gprt, x1g, 1.f/(float)K1V);

  // ---- block 2: SAGE -> SAGPool(205) -> gap  (F1 -> F2) ----
  k_sage_agg<<<(NBV*32)/256, 256, 0, stream>>>(F1, nmask, rp, csr_src, AGG, 1);
  k_gemm<<<NBV/128, 512, 0, stream>>>(AGG, F1, c2_wl, c2_wr, c2_bl, F2, 1, 1, 1);
  k_qr<<<(NBV*32)/256, 256, 0, stream>>>(F2, p2_wrel, p2_wroot, qv, rv);
  k_gconv<<<NBV/256, 256, 0, stream>>>(qv, rv, nmask, rp, csr_src, p2_brel, sA);
  k_pool<<<BV, 512, 0, stream>>>(sA, nmask, sel, K2V);
  k_scale_part<<<BV*8, 128, 0, stream>>>(F2, sel, gprt);
  k_gap_final<<<BV, 128, 0, stream>>>(gprt, x2g, 1.f/(float)K2V);

  // ---- block 3: GAT -> SAGPool(103) -> gap  (F2 -> xs=AGG -> F1) ----
  k_gemm<<<NBV/128, 512, 0, stream>>>(F2, F2, g_w, g_w, g_b, AGG, 0, 0, 0);  // xs = F2 @ g_w
  k_heads<<<(NBV*4)/256, 256, 0, stream>>>(AGG, g_as, g_ad, alS, alD);
  k_ea_part<<<256, 256, 0, stream>>>(ea, srcA, dstA, nmask, eprt);
  k_ea_final<<<1, 64, 0, stream>>>(eprt, sml+8);
  k_alse<<<1, 64, 0, stream>>>(sml+8, sml+20, sml+16);
  k_gat<<<(NBV*32)/256, 256, 0, stream>>>(AGG, alS, alD, ALE, nmask, rp, csr_src, csr_eid, sml+16, g_b, F1);
  k_qr<<<(NBV*32)/256, 256, 0, stream>>>(F1, p3_wrel, p3_wroot, qv, rv);
  k_gconv<<<NBV/256, 256, 0, stream>>>(qv, rv, nmask, rp, csr_src, p3_brel, sA);
  k_pool<<<BV, 512, 0, stream>>>(sA, nmask, sel, K3V);
  k_scale_part<<<BV*8, 128, 0, stream>>>(F1, sel, gprt);
  k_gap_final<<<BV, 128, 0, stream>>>(gprt, x3g, 1.f/(float)K3V);

  // ---- readout MLP ----
  k_mlp<<<BV, 128, 0, stream>>>(x1g, x2g, x3g, l1_w, l1_b, l2_w, l2_b, l3_w, l3_b, out);
}

// Round 12
// 693.069 us; speedup vs baseline: 2.2109x; 1.0437x over previous
//
#include <hip/hip_runtime.h>
#include <math.h>

#define NBV 65536
#define EV  1048576
#define BV  128
#define K1V 410
#define K2V 205
#define K3V 103
#define NEG_BIG (-1.0e38f)

__device__ __forceinline__ float lrelu(float x){ return x > 0.f ? x : 0.2f*x; }

// ---------------- diagnostics sentinel ----------------
__global__ void k_sentinel(float* out, float v){
  int i = threadIdx.x;
  if (i < 128) out[i] = v;
}

// ---------------- utility ----------------
__global__ void k_fill1(float* p, int n){
  int i = blockIdx.x*blockDim.x + threadIdx.x;
  if (i < n) p[i] = 1.f;
}

__global__ void k_zero_i(int* p, int n){
  int i = blockIdx.x*blockDim.x + threadIdx.x;
  if (i < n) p[i] = 0;
}

// ---------------- CSR build (int atomics only) ----------------
__global__ void k_hist(const int* dst, int* dcnt){
  int e = blockIdx.x*blockDim.x + threadIdx.x;
  if (e < EV) atomicAdd(&dcnt[dst[e]], 1);
}

__global__ void k_scan1(const int* dcnt, int* rp, int* bsum){
  __shared__ int sc[256];
  int t = threadIdx.x, i = blockIdx.x*256 + t;
  int v = dcnt[i];
  sc[t] = v; __syncthreads();
  for (int o = 1; o < 256; o <<= 1){
    int x = (t >= o) ? sc[t-o] : 0;
    __syncthreads();
    sc[t] += x;
    __syncthreads();
  }
  rp[i] = sc[t];
  if (t == 255) bsum[blockIdx.x] = sc[t];
}

__global__ void k_scan2(int* bsum){
  __shared__ int sc[256];
  int t = threadIdx.x;
  int v = bsum[t];
  sc[t] = v; __syncthreads();
  for (int o = 1; o < 256; o <<= 1){
    int x = (t >= o) ? sc[t-o] : 0;
    __syncthreads();
    sc[t] += x;
    __syncthreads();
  }
  bsum[t] = sc[t] - v;
}

__global__ void k_scan3(int* rp, const int* dcnt, const int* bsum){
  int t = threadIdx.x, i = blockIdx.x*256 + t;
  rp[i] = rp[i] - dcnt[i] + bsum[blockIdx.x];
  if (i == 0) rp[NBV] = EV;
}

__global__ void k_scatter(const int* src, const int* dst, const int* rp, int* fill,
                          int* csr_src, int* csr_eid){
  int e = blockIdx.x*blockDim.x + threadIdx.x;
  if (e < EV){
    int d = dst[e];
    int pos = atomicAdd(&fill[d], 1);
    int slot = rp[d] + pos;
    csr_src[slot] = src[e];
    csr_eid[slot] = e;
  }
}

// ---------------- small precomputes ----------------
__global__ void k_invnorm(const float* wv, float* outv){
  __shared__ float sc[128];
  int t = threadIdx.x;
  float v = wv[t];
  sc[t] = v*v; __syncthreads();
  for (int o = 64; o > 0; o >>= 1){ if (t < o) sc[t] += sc[t+o]; __syncthreads(); }
  if (t == 0) outv[0] = 1.f / sqrtf(sc[0]);
}

__global__ void k_ve(const float* g_we, const float* g_ae, float* ve){
  int t = threadIdx.x;
  if (t < 28){
    int ed = t >> 2, h = t & 3;
    float a = 0.f;
    for (int c = 0; c < 32; c++) a += g_we[ed*128 + h*32 + c] * g_ae[h*32 + c];
    ve[t] = a;
  }
}

__global__ void k_ale(const float* ea, const float* ve, float* ALE){
  int e = blockIdx.x*blockDim.x + threadIdx.x;
  if (e < EV){
    float a0=0.f,a1=0.f,a2=0.f,a3=0.f;
    for (int ed = 0; ed < 7; ed++){
      float x = ea[e*7 + ed];
      a0 += x*ve[ed*4+0]; a1 += x*ve[ed*4+1]; a2 += x*ve[ed*4+2]; a3 += x*ve[ed*4+3];
    }
    float4 o; o.x=a0; o.y=a1; o.z=a2; o.w=a3;
    *(float4*)&ALE[(size_t)e*4] = o;
  }
}

// ---------------- SAGE mean aggregation (XCD-swizzled, 4-deep gather) ----------------
__global__ void __launch_bounds__(256) k_sage_agg(const float* X, const float* nmask,
    const int* rp, const int* csr_src, float* AGG, int masked){
  int g = blockIdx.x & 127;
  int blk = blockIdx.x >> 7;
  int i = g*512 + blk*8 + (threadIdx.x >> 5);
  int c4 = threadIdx.x & 31;
  float ax=0.f,ay=0.f,az=0.f,aw=0.f,cnt=0.f;
  if (!masked || nmask[i] > 0.f){
    int r0 = rp[i], r1 = rp[i+1];
    int s = r0;
    for (; s + 4 <= r1; s += 4){
      int sn0 = csr_src[s+0], sn1 = csr_src[s+1], sn2 = csr_src[s+2], sn3 = csr_src[s+3];
      float4 v0 = *(const float4*)&X[((size_t)sn0 << 7) + (c4 << 2)];
      float4 v1 = *(const float4*)&X[((size_t)sn1 << 7) + (c4 << 2)];
      float4 v2 = *(const float4*)&X[((size_t)sn2 << 7) + (c4 << 2)];
      float4 v3 = *(const float4*)&X[((size_t)sn3 << 7) + (c4 << 2)];
      float nm0 = masked ? nmask[sn0] : 1.f;
      float nm1 = masked ? nmask[sn1] : 1.f;
      float nm2 = masked ? nmask[sn2] : 1.f;
      float nm3 = masked ? nmask[sn3] : 1.f;
      if (nm0 > 0.f){ ax += v0.x; ay += v0.y; az += v0.z; aw += v0.w; cnt += 1.f; }
      if (nm1 > 0.f){ ax += v1.x; ay += v1.y; az += v1.z; aw += v1.w; cnt += 1.f; }
      if (nm2 > 0.f){ ax += v2.x; ay += v2.y; az += v2.z; aw += v2.w; cnt += 1.f; }
      if (nm3 > 0.f){ ax += v3.x; ay += v3.y; az += v3.z; aw += v3.w; cnt += 1.f; }
    }
    for (; s < r1; s++){
      int sn = csr_src[s];
      float nm = masked ? nmask[sn] : 1.f;
      if (nm > 0.f){
        const float4 v = *(const float4*)&X[((size_t)sn << 7) + (c4 << 2)];
        ax += v.x; ay += v.y; az += v.z; aw += v.w; cnt += 1.f;
      }
    }
  }
  float inv = 1.f / fmaxf(cnt, 1.f);
  float4 o; o.x = ax*inv; o.y = ay*inv; o.z = az*inv; o.w = aw*inv;
  *(float4*)&AGG[((size_t)i << 7) + (c4 << 2)] = o;
}

// ---------------- dual GEMM f32, W-resident, register-parked A pipeline ----------------
// rA(chunk c+1) loads overlap compute of chunk c — the global latency that was
// exposed between barriers in r11 (VALUBusy 46%) now hides behind 16-kk FMA bursts.
__global__ void __launch_bounds__(512) k_gemm(const float* A1, const float* A2,
    const float* W1, const float* W2, const float* bias,
    float* OUT, int has2, int relu, int hasb){
  __shared__ float ws[128][128];
  __shared__ float as[16][136];
  int t = threadIdx.x;
  int n0 = blockIdx.x * 128;
  int rowg = t >> 5;
  int colg = t & 31;
  int rb = rowg * 8;
  int jb = colg * 4;
  int an = t >> 2;              // A-stage row 0..127
  int ak = (t & 3) << 2;        // A-stage k offset {0,4,8,12}
  float acc[8][4];
  for (int r = 0; r < 8; r++)
    for (int j = 0; j < 4; j++) acc[r][j] = 0.f;
  int nmat = has2 ? 2 : 1;
  for (int m = 0; m < nmat; m++){
    const float* A = (m == 0) ? A1 : A2;
    const float* W = (m == 0) ? W1 : W2;
    __syncthreads();   // prior readers of ws/as done (no-op cost at m==0)
    for (int ii = 0; ii < 8; ii++){
      int idx4 = t + 512*ii;
      int kk = idx4 >> 5;
      int jj = (idx4 & 31) << 2;
      *(float4*)&ws[kk][jj] = *(const float4*)&W[kk*128 + jj];
    }
    float4 rA = *(const float4*)&A[((size_t)(n0+an) << 7) + ak];   // chunk 0
    for (int c = 0; c < 8; c++){
      if (c > 0) __syncthreads();        // prior compute done reading as
      as[ak+0][an] = rA.x;
      as[ak+1][an] = rA.y;
      as[ak+2][an] = rA.z;
      as[ak+3][an] = rA.w;
      __syncthreads();                   // as (and ws on c==0) visible
      if (c+1 < 8)
        rA = *(const float4*)&A[((size_t)(n0+an) << 7) + (c+1)*16 + ak];  // prefetch
      int kb = c*16;
      for (int kk = 0; kk < 16; kk++){
        float4 wv = *(const float4*)&ws[kb+kk][jb];
        float4 aL = *(const float4*)&as[kk][rb];
        float4 aH = *(const float4*)&as[kk][rb+4];
        float a0=aL.x,a1=aL.y,a2=aL.z,a3=aL.w,a4=aH.x,a5=aH.y,a6=aH.z,a7=aH.w;
        acc[0][0]+=a0*wv.x; acc[0][1]+=a0*wv.y; acc[0][2]+=a0*wv.z; acc[0][3]+=a0*wv.w;
        acc[1][0]+=a1*wv.x; acc[1][1]+=a1*wv.y; acc[1][2]+=a1*wv.z; acc[1][3]+=a1*wv.w;
        acc[2][0]+=a2*wv.x; acc[2][1]+=a2*wv.y; acc[2][2]+=a2*wv.z; acc[2][3]+=a2*wv.w;
        acc[3][0]+=a3*wv.x; acc[3][1]+=a3*wv.y; acc[3][2]+=a3*wv.z; acc[3][3]+=a3*wv.w;
        acc[4][0]+=a4*wv.x; acc[4][1]+=a4*wv.y; acc[4][2]+=a4*wv.z; acc[4][3]+=a4*wv.w;
        acc[5][0]+=a5*wv.x; acc[5][1]+=a5*wv.y; acc[5][2]+=a5*wv.z; acc[5][3]+=a5*wv.w;
        acc[6][0]+=a6*wv.x; acc[6][1]+=a6*wv.y; acc[6][2]+=a6*wv.z; acc[6][3]+=a6*wv.w;
        acc[7][0]+=a7*wv.x; acc[7][1]+=a7*wv.y; acc[7][2]+=a7*wv.z; acc[7][3]+=a7*wv.w;
      }
    }
  }
  float bj0=0.f,bj1=0.f,bj2=0.f,bj3=0.f;
  if (hasb){
    bj0 = bias[jb+0]; bj1 = bias[jb+1]; bj2 = bias[jb+2]; bj3 = bias[jb+3];
  }
  for (int r = 0; r < 8; r++){
    float4 o;
    o.x = acc[r][0]+bj0; o.y = acc[r][1]+bj1; o.z = acc[r][2]+bj2; o.w = acc[r][3]+bj3;
    if (relu){
      o.x = fmaxf(o.x,0.f); o.y = fmaxf(o.y,0.f); o.z = fmaxf(o.z,0.f); o.w = fmaxf(o.w,0.f);
    }
    *(float4*)&OUT[((size_t)(n0+rb+r) << 7) + jb] = o;
  }
}

// ---------------- scores (32 lanes/node, shfl reduce) ----------------
__global__ void __launch_bounds__(256) k_score1(const float* X, const float* pw, const float* invn, float* s){
  int gid = blockIdx.x*256 + threadIdx.x;
  int i = gid >> 5, c4 = gid & 31;
  float4 v = *(const float4*)&X[((size_t)i << 7) + (c4 << 2)];
  float4 wv = *(const float4*)&pw[c4 << 2];
  float a = v.x*wv.x + v.y*wv.y + v.z*wv.z + v.w*wv.w;
  for (int o = 16; o > 0; o >>= 1) a += __shfl_down(a, o, 32);
  if (c4 == 0) s[i] = tanhf(a * invn[0]);
}

__global__ void __launch_bounds__(256) k_qr(const float* X, const float* wrel, const float* wroot,
                                            float* q, float* r){
  int gid = blockIdx.x*256 + threadIdx.x;
  int i = gid >> 5, c4 = gid & 31;
  float4 v = *(const float4*)&X[((size_t)i << 7) + (c4 << 2)];
  float4 wa = *(const float4*)&wrel[c4 << 2];
  float4 wb = *(const float4*)&wroot[c4 << 2];
  float aq = v.x*wa.x + v.y*wa.y + v.z*wa.z + v.w*wa.w;
  float ar = v.x*wb.x + v.y*wb.y + v.z*wb.z + v.w*wb.w;
  for (int o = 16; o > 0; o >>= 1){
    aq += __shfl_down(aq, o, 32);
    ar += __shfl_down(ar, o, 32);
  }
  if (c4 == 0){ q[i] = aq; r[i] = ar; }
}

__global__ void k_gconv(const float* q, const float* r, const float* nmask,
    const int* rp, const int* csr_src, const float* brel, float* s){
  int i = blockIdx.x*blockDim.x + threadIdx.x;
  if (i >= NBV) return;
  float acc = 0.f;
  if (nmask[i] > 0.f){
    int r0 = rp[i], r1 = rp[i+1];
    int t2 = r0;
    for (; t2 + 4 <= r1; t2 += 4){
      int sn0 = csr_src[t2+0], sn1 = csr_src[t2+1], sn2 = csr_src[t2+2], sn3 = csr_src[t2+3];
      float nm0 = nmask[sn0], nm1 = nmask[sn1], nm2 = nmask[sn2], nm3 = nmask[sn3];
      float q0 = q[sn0], q1 = q[sn1], q2 = q[sn2], q3 = q[sn3];
      if (nm0 > 0.f) acc += q0;
      if (nm1 > 0.f) acc += q1;
      if (nm2 > 0.f) acc += q2;
      if (nm3 > 0.f) acc += q3;
    }
    for (; t2 < r1; t2++){
      int sn = csr_src[t2];
      if (nmask[sn] > 0.f) acc += q[sn];
    }
  }
  s[i] = tanhf(acc + brel[0] + r[i]);
}

// ---------------- top-k pool (stable tie-break == jax.lax.top_k) ----------------
__global__ void __launch_bounds__(512) k_pool(const float* s, float* nmask, float* sel, int K){
  __shared__ float sc[512];
  int b = blockIdx.x, t = threadIdx.x;
  int i = b*512 + t;
  float nm = nmask[i];
  float sv = s[i];
  float ms = (nm > 0.f) ? sv : NEG_BIG;
  sc[t] = ms;
  __syncthreads();
  int rank = 0;
  for (int j = 0; j < 512; j++){
    float o = sc[j];
    rank += ((o > ms) || (o == ms && j < t)) ? 1 : 0;
  }
  bool selb = rank < K;
  nmask[i] = selb ? 1.f : 0.f;
  sel[i] = selb ? sv : 0.f;
}

// scale kept rows by score (in place) + gap partials — no atomics.
__global__ void __launch_bounds__(128) k_scale_part(float* X, const float* sel, float* part){
  int b = blockIdx.x >> 3, q = blockIdx.x & 7, c = threadIdx.x;
  float acc = 0.f;
  for (int n = q*64; n < q*64 + 64; n++){
    int i = b*512 + n;
    float v = X[((size_t)i << 7) + c] * sel[i];
    X[((size_t)i << 7) + c] = v;
    acc += v;
  }
  part[(size_t)blockIdx.x*128 + c] = acc;
}

__global__ void __launch_bounds__(128) k_gap_final(const float* part, float* gap, float invK){
  int b = blockIdx.x, c = threadIdx.x;
  float s = 0.f;
  for (int q = 0; q < 8; q++) s += part[(size_t)(b*8+q)*128 + c];
  gap[b*128 + c] = s * invK;
}

// ---------------- GAT pieces ----------------
__global__ void k_heads(const float* xs, const float* a_s, const float* a_d,
                        float* alS, float* alD){
  int gid = blockIdx.x*blockDim.x + threadIdx.x;
  int i = gid >> 2, h = gid & 3;
  if (i >= NBV) return;
  const float4* xr = (const float4*)&xs[((size_t)i << 7) + h*32];
  const float4* wa = (const float4*)&a_s[h*32];
  const float4* wd = (const float4*)&a_d[h*32];
  float as_ = 0.f, ad_ = 0.f;
  for (int c4 = 0; c4 < 8; c4++){
    float4 v = xr[c4]; float4 A = wa[c4]; float4 D = wd[c4];
    as_ += v.x*A.x + v.y*A.y + v.z*A.z + v.w*A.w;
    ad_ += v.x*D.x + v.y*D.y + v.z*D.z + v.w*D.w;
  }
  alS[gid] = as_; alD[gid] = ad_;
}

// edge-attr masked mean: per-block partials (no atomics)
__global__ void __launch_bounds__(256) k_ea_part(const float* ea, const int* srcA, const int* dstA,
    const float* nmask, float* part){
  float p[8] = {0.f,0.f,0.f,0.f,0.f,0.f,0.f,0.f};
  for (int e = blockIdx.x*256 + threadIdx.x; e < EV; e += 256*256){
    if (nmask[srcA[e]] > 0.f && nmask[dstA[e]] > 0.f){
      for (int d = 0; d < 7; d++) p[d] += ea[e*7 + d];
      p[7] += 1.f;
    }
  }
  __shared__ float red[256];
  for (int comp = 0; comp < 8; comp++){
    red[threadIdx.x] = p[comp]; __syncthreads();
    for (int o = 128; o > 0; o >>= 1){ if (threadIdx.x < o) red[threadIdx.x] += red[threadIdx.x + o]; __syncthreads(); }
    if (threadIdx.x == 0) part[blockIdx.x*8 + comp] = red[0];
    __syncthreads();
  }
}

__global__ void k_ea_final(const float* part, float* easum){
  int h = threadIdx.x;
  if (h < 8){
    float s = 0.f;
    for (int b = 0; b < 256; b++) s += part[b*8 + h];
    easum[h] = s;
  }
}

__global__ void k_alse(const float* easum, const float* ve, float* alse){
  if (threadIdx.x == 0 && blockIdx.x == 0){
    float cnt = fmaxf(easum[7], 1.f);
    for (int h = 0; h < 4; h++){
      float s = 0.f;
      for (int ed = 0; ed < 7; ed++) s += (easum[ed]/cnt) * ve[ed*4 + h];
      alse[h] = s;
    }
  }
}

// GAT: 32 threads/node, XCD-swizzled, 4-deep gathers + in-order online softmax.
__global__ void __launch_bounds__(256) k_gat(const float* xs, const float* alS, const float* alD,
    const float* ALE, const float* nmask, const int* rp, const int* csr_src,
    const int* csr_eid, const float* alse, const float* g_b, float* OUT){
  int g = blockIdx.x & 127;
  int blk = blockIdx.x >> 7;
  int i = g*512 + blk*8 + (threadIdx.x >> 5);
  int lane = threadIdx.x & 31;
  int h = lane >> 3;
  int cidx = h*8 + (lane & 7);
  float nmi = nmask[i];
  const float4* xs4 = (const float4*)xs;
  float m = 0.f, den = 0.f;
  float4 acc; acc.x=0.f; acc.y=0.f; acc.z=0.f; acc.w=0.f;
  if (nmi > 0.f){
    float ald_i = alD[i*4 + h];
    m = lrelu(alS[i*4 + h] + ald_i + alse[h]);   // aself
    den = 1.f;
    acc = xs4[(size_t)i*32 + cidx];
    int r0 = rp[i], r1 = rp[i+1];
    int s = r0;
    for (; s + 4 <= r1; s += 4){
      int sn0 = csr_src[s+0], sn1 = csr_src[s+1], sn2 = csr_src[s+2], sn3 = csr_src[s+3];
      int e0 = csr_eid[s+0], e1 = csr_eid[s+1], e2 = csr_eid[s+2], e3 = csr_eid[s+3];
      float nm0 = nmask[sn0], nm1 = nmask[sn1], nm2 = nmask[sn2], nm3 = nmask[sn3];
      float al0 = alS[sn0*4 + h], al1 = alS[sn1*4 + h], al2 = alS[sn2*4 + h], al3 = alS[sn3*4 + h];
      float ae0 = ALE[(size_t)e0*4 + h], ae1 = ALE[(size_t)e1*4 + h];
      float ae2 = ALE[(size_t)e2*4 + h], ae3 = ALE[(size_t)e3*4 + h];
      float4 v0 = xs4[(size_t)sn0*32 + cidx];
      float4 v1 = xs4[(size_t)sn1*32 + cidx];
      float4 v2 = xs4[(size_t)sn2*32 + cidx];
      float4 v3 = xs4[(size_t)sn3*32 + cidx];
      if (nm0 > 0.f){
        float a = lrelu(al0 + ald_i + ae0);
        float mn = fmaxf(m, a); float pm = expf(m - mn); float pa = expf(a - mn);
        den = den*pm + pa;
        acc.x = acc.x*pm + pa*v0.x; acc.y = acc.y*pm + pa*v0.y;
        acc.z = acc.z*pm + pa*v0.z; acc.w = acc.w*pm + pa*v0.w;
        m = mn;
      }
      if (nm1 > 0.f){
        float a = lrelu(al1 + ald_i + ae1);
        float mn = fmaxf(m, a); float pm = expf(m - mn); float pa = expf(a - mn);
        den = den*pm + pa;
        acc.x = acc.x*pm + pa*v1.x; acc.y = acc.y*pm + pa*v1.y;
        acc.z = acc.z*pm + pa*v1.z; acc.w = acc.w*pm + pa*v1.w;
        m = mn;
      }
      if (nm2 > 0.f){
        float a = lrelu(al2 + ald_i + ae2);
        float mn = fmaxf(m, a); float pm = expf(m - mn); float pa = expf(a - mn);
        den = den*pm + pa;
        acc.x = acc.x*pm + pa*v2.x; acc.y = acc.y*pm + pa*v2.y;
        acc.z = acc.z*pm + pa*v2.z; acc.w = acc.w*pm + pa*v2.w;
        m = mn;
      }
      if (nm3 > 0.f){
        float a = lrelu(al3 + ald_i + ae3);
        float mn = fmaxf(m, a); float pm = expf(m - mn); float pa = expf(a - mn);
        den = den*pm + pa;
        acc.x = acc.x*pm + pa*v3.x; acc.y = acc.y*pm + pa*v3.y;
        acc.z = acc.z*pm + pa*v3.z; acc.w = acc.w*pm + pa*v3.w;
        m = mn;
      }
    }
    for (; s < r1; s++){
      int sn = csr_src[s];
      if (nmask[sn] > 0.f){
        float a = lrelu(alS[sn*4 + h] + ald_i + ALE[(size_t)csr_eid[s]*4 + h]);
        float4 v = xs4[(size_t)sn*32 + cidx];
        float mn = fmaxf(m, a); float pm = expf(m - mn); float pa = expf(a - mn);
        den = den*pm + pa;
        acc.x = acc.x*pm + pa*v.x; acc.y = acc.y*pm + pa*v.y;
        acc.z = acc.z*pm + pa*v.z; acc.w = acc.w*pm + pa*v.w;
        m = mn;
      }
    }
  }
  den = fmaxf(den, 1e-16f);
  float rd = 1.f/den;
  int cb = cidx << 2;
  float4 o;
  o.x = fmaxf(acc.x*rd + g_b[cb+0], 0.f);
  o.y = fmaxf(acc.y*rd + g_b[cb+1], 0.f);
  o.z = fmaxf(acc.z*rd + g_b[cb+2], 0.f);
  o.w = fmaxf(acc.w*rd + g_b[cb+3], 0.f);
  *(float4*)&OUT[((size_t)i << 7) + cb] = o;
}

// ---------------- final MLP ----------------
__global__ void __launch_bounds__(128) k_mlp(const float* x1g, const float* x2g, const float* x3g,
    const float* l1w, const float* l1b, const float* l2w, const float* l2b,
    const float* l3w, const float* l3b, float* out){
  __shared__ float hh[128];
  __shared__ float h2[128];
  __shared__ float h3[64];
  int b = blockIdx.x, t = threadIdx.x;
  hh[t] = x1g[b*128 + t] + x2g[b*128 + t] + x3g[b*128 + t];
  __syncthreads();
  float a = l1b[t];
  for (int k = 0; k < 128; k++) a += hh[k] * l1w[k*128 + t];
  h2[t] = fmaxf(a, 0.f);
  __syncthreads();
  if (t < 64){
    float a2 = l2b[t];
    for (int k = 0; k < 128; k++) a2 += h2[k] * l2w[k*64 + t];
    h3[t] = fmaxf(a2, 0.f);
  }
  __syncthreads();
  if (t == 0){
    float z = l3b[0];
    for (int k = 0; k < 64; k++) z += h3[k] * l3w[k];
    out[b] = 1.f/(1.f + expf(-z));
  }
}

// ---------------- launch ----------------
extern "C" void kernel_launch(void* const* d_in, const int* in_sizes, int n_in,
                              void* d_out, int out_size, void* d_ws, size_t ws_size,
                              hipStream_t stream){
  const float* x       = (const float*)d_in[0];
  const int*   ei      = (const int*)d_in[1];
  const float* ea      = (const float*)d_in[2];
  const float* c1_wl   = (const float*)d_in[3];
  const float* c1_bl   = (const float*)d_in[4];
  const float* c1_wr   = (const float*)d_in[5];
  const float* p1_w    = (const float*)d_in[6];
  const float* c2_wl   = (const float*)d_in[7];
  const float* c2_bl   = (const float*)d_in[8];
  const float* c2_wr   = (const float*)d_in[9];
  const float* p2_wrel = (const float*)d_in[10];
  const float* p2_brel = (const float*)d_in[11];
  const float* p2_wroot= (const float*)d_in[12];
  const float* g_w     = (const float*)d_in[13];
  const float* g_as    = (const float*)d_in[14];
  const float* g_ad    = (const float*)d_in[15];
  const float* g_we    = (const float*)d_in[16];
  const float* g_ae    = (const float*)d_in[17];
  const float* g_b     = (const float*)d_in[18];
  const float* p3_wrel = (const float*)d_in[19];
  const float* p3_brel = (const float*)d_in[20];
  const float* p3_wroot= (const float*)d_in[21];
  const float* l1_w    = (const float*)d_in[22];
  const float* l1_b    = (const float*)d_in[23];
  const float* l2_w    = (const float*)d_in[24];
  const float* l2_b    = (const float*)d_in[25];
  const float* l3_w    = (const float*)d_in[26];
  const float* l3_b    = (const float*)d_in[27];
  float* out = (float*)d_out;
  (void)in_sizes; (void)n_in; (void)out_size;

  // Workspace layout (f32, ~137 MB)
  char* w = (char*)d_ws;
  size_t off = 0;
  float* AGG  = (float*)(w + off); off += (size_t)NBV*128*4;
  float* F1   = (float*)(w + off); off += (size_t)NBV*128*4;
  float* F2   = (float*)(w + off); off += (size_t)NBV*128*4;
  float* ALE  = (float*)(w + off); off += (size_t)EV*4*4;
  float* sA   = (float*)(w + off); off += (size_t)NBV*4;
  float* sel  = (float*)(w + off); off += (size_t)NBV*4;
  float* qv   = (float*)(w + off); off += (size_t)NBV*4;
  float* rv   = (float*)(w + off); off += (size_t)NBV*4;
  float* nmask= (float*)(w + off); off += (size_t)NBV*4;
  float* alS  = (float*)(w + off); off += (size_t)NBV*4*4;
  float* alD  = (float*)(w + off); off += (size_t)NBV*4*4;
  float* x1g  = (float*)(w + off); off += (size_t)BV*128*4;
  float* x2g  = (float*)(w + off); off += (size_t)BV*128*4;
  float* x3g  = (float*)(w + off); off += (size_t)BV*128*4;
  float* sml  = (float*)(w + off); off += 64*4;      // [0]=invnorm [8..15]=easum [16..19]=alse [20..47]=ve
  float* eprt = (float*)(w + off); off += 2048*4;
  float* gprt = (float*)(w + off); off += (size_t)1024*128*4;
  int* csr_src = (int*)(w + off); off += (size_t)EV*4;
  int* csr_eid = (int*)(w + off); off += (size_t)EV*4;
  int* rp      = (int*)(w + off); off += (size_t)(NBV+64)*4;
  int* dcnt    = (int*)(w + off); off += (size_t)(NBV+64)*4;
  int* bsum    = (int*)(w + off); off += 1024;
  size_t needed = off;

  float sentinel = (ws_size >= needed) ? 0.125f : 0.875f;
  k_sentinel<<<1, 128, 0, stream>>>(out, sentinel);

  const int* srcA = ei;
  const int* dstA = ei + EV;

  // ---- setup ----
  k_fill1<<<NBV/256, 256, 0, stream>>>(nmask, NBV);
  k_zero_i<<<(NBV+256)/256, 256, 0, stream>>>(dcnt, NBV+1);
  k_hist<<<EV/256, 256, 0, stream>>>(dstA, dcnt);
  k_scan1<<<256, 256, 0, stream>>>(dcnt, rp, bsum);
  k_scan2<<<1, 256, 0, stream>>>(bsum);
  k_scan3<<<256, 256, 0, stream>>>(rp, dcnt, bsum);
  k_zero_i<<<(NBV+256)/256, 256, 0, stream>>>(dcnt, NBV+1);
  k_scatter<<<EV/256, 256, 0, stream>>>(srcA, dstA, rp, dcnt, csr_src, csr_eid);
  k_ve<<<1, 32, 0, stream>>>(g_we, g_ae, sml+20);
  k_ale<<<EV/256, 256, 0, stream>>>(ea, sml+20, ALE);

  // ---- block 1: SAGE -> TopK(410) -> gap  (x -> F1) ----
  k_invnorm<<<1, 128, 0, stream>>>(p1_w, sml);
  k_sage_agg<<<(NBV*32)/256, 256, 0, stream>>>(x, nmask, rp, csr_src, AGG, 0);
  k_gemm<<<NBV/128, 512, 0, stream>>>(AGG, x, c1_wl, c1_wr, c1_bl, F1, 1, 1, 1);
  k_score1<<<(NBV*32)/256, 256, 0, stream>>>(F1, p1_w, sml, sA);
  k_pool<<<BV, 512, 0, stream>>>(sA, nmask, sel, K1V);
  k_scale_part<<<BV*8, 128, 0, stream>>>(F1, sel, gprt);
  k_gap_final<<<BV, 128, 0, stream>>>(gprt, x1g, 1.f/(float)K1V);

  // ---- block 2: SAGE -> SAGPool(205) -> gap  (F1 -> F2) ----
  k_sage_agg<<<(NBV*32)/256, 256, 0, stream>>>(F1, nmask, rp, csr_src, AGG, 1);
  k_gemm<<<NBV/128, 512, 0, stream>>>(AGG, F1, c2_wl, c2_wr, c2_bl, F2, 1, 1, 1);
  k_qr<<<(NBV*32)/256, 256, 0, stream>>>(F2, p2_wrel, p2_wroot, qv, rv);
  k_gconv<<<NBV/256, 256, 0, stream>>>(qv, rv, nmask, rp, csr_src, p2_brel, sA);
  k_pool<<<BV, 512, 0, stream>>>(sA, nmask, sel, K2V);
  k_scale_part<<<BV*8, 128, 0, stream>>>(F2, sel, gprt);
  k_gap_final<<<BV, 128, 0, stream>>>(gprt, x2g, 1.f/(float)K2V);

  // ---- block 3: GAT -> SAGPool(103) -> gap  (F2 -> xs=AGG -> F1) ----
  k_gemm<<<NBV/128, 512, 0, stream>>>(F2, F2, g_w, g_w, g_b, AGG, 0, 0, 0);  // xs = F2 @ g_w
  k_heads<<<(NBV*4)/256, 256, 0, stream>>>(AGG, g_as, g_ad, alS, alD);
  k_ea_part<<<256, 256, 0, stream>>>(ea, srcA, dstA, nmask, eprt);
  k_ea_final<<<1, 64, 0, stream>>>(eprt, sml+8);
  k_alse<<<1, 64, 0, stream>>>(sml+8, sml+20, sml+16);
  k_gat<<<(NBV*32)/256, 256, 0, stream>>>(AGG, alS, alD, ALE, nmask, rp, csr_src, csr_eid, sml+16, g_b, F1);
  k_qr<<<(NBV*32)/256, 256, 0, stream>>>(F1, p3_wrel, p3_wroot, qv, rv);
  k_gconv<<<NBV/256, 256, 0, stream>>>(qv, rv, nmask, rp, csr_src, p3_brel, sA);
  k_pool<<<BV, 512, 0, stream>>>(sA, nmask, sel, K3V);
  k_scale_part<<<BV*8, 128, 0, stream>>>(F1, sel, gprt);
  k_gap_final<<<BV, 128, 0, stream>>>(gprt, x3g, 1.f/(float)K3V);

  // ---- readout MLP ----
  k_mlp<<<BV, 128, 0, stream>>>(x1g, x2g, x3g, l1_w, l1_b, l2_w, l2_b, l3_w, l3_b, out);
}